// Round 1
// baseline (281.733 us; speedup 1.0000x reference)
//
#include <hip/hip_runtime.h>
#include <stdint.h>

// LATENT=128, HIDDEN=2048, N_PARTS=128, K=2048
// outputs: omega(1152,2048) transf(1536,2048) rot(1152,2048) transl(384,2048)

typedef short bf16x8 __attribute__((ext_vector_type(8)));
typedef float f32x4 __attribute__((ext_vector_type(4)));

__device__ __forceinline__ unsigned short f2bf(float f) {
  unsigned int x = __float_as_uint(f);
  unsigned int r = (x + 0x7fffu + ((x >> 16) & 1u)) >> 16;
  return (unsigned short)r;
}

__device__ __forceinline__ void gld_lds16(const void* g, void* l) {
  __builtin_amdgcn_global_load_lds(
      (__attribute__((address_space(1))) void*)(g),
      (__attribute__((address_space(3))) void*)(l),
      16, 0, 0);
}

// ---------------------------------------------------------------------------
// Prep: blocks 0..9983 cast all 8 weights fp32->bf16 (8 elems/thread, 16 B
// stores); blocks 9984..10239 transpose+cast x (128x2048) -> Xt (2048x128).
__global__ void prep_k(const float* __restrict__ x,
                       const float* __restrict__ wo0, const float* __restrict__ wo1,
                       const float* __restrict__ wo2, const float* __restrict__ wo3,
                       const float* __restrict__ wt0, const float* __restrict__ wt1,
                       const float* __restrict__ wt2, const float* __restrict__ wt3,
                       unsigned short* __restrict__ dst, unsigned short* __restrict__ xt) {
  __shared__ float tile[32][33];
  const int b = blockIdx.x;
  const int tid = threadIdx.x;
  if (b >= 9984) {
    const int r = b - 9984;
    const int bx = r & 63, by = r >> 6;
    const int tx = tid & 31, ty = tid >> 5;
#pragma unroll
    for (int i = 0; i < 32; i += 8)
      tile[ty + i][tx] = x[(size_t)(by * 32 + ty + i) * 2048 + bx * 32 + tx];
    __syncthreads();
#pragma unroll
    for (int i = 0; i < 32; i += 8)
      xt[(size_t)(bx * 32 + ty + i) * 128 + by * 32 + tx] = f2bf(tile[tx][ty + i]);
    return;
  }
  int idx = (b * 256 + tid) * 8;
  if (idx >= 20447232) return;
  const float* src;
  int off;
  if (idx < 8650752) {
    if (idx < 262144)       { src = wo0; off = idx; }
    else if (idx < 4456448) { src = wo1; off = idx - 262144; }
    else                    { src = wo2; off = idx - 4456448; }
  } else {
    if (idx < 11010048)      { src = wo3; off = idx - 8650752; }
    else if (idx < 11272192) { src = wt0; off = idx - 11010048; }
    else if (idx < 15466496) { src = wt1; off = idx - 11272192; }
    else if (idx < 19660800) { src = wt2; off = idx - 15466496; }
    else                     { src = wt3; off = idx - 19660800; }
  }
  float4 a = *(const float4*)(src + off);
  float4 c = *(const float4*)(src + off + 4);
  uint4 o;
  o.x = (unsigned)f2bf(a.x) | ((unsigned)f2bf(a.y) << 16);
  o.y = (unsigned)f2bf(a.z) | ((unsigned)f2bf(a.w) << 16);
  o.z = (unsigned)f2bf(c.x) | ((unsigned)f2bf(c.y) << 16);
  o.w = (unsigned)f2bf(c.z) | ((unsigned)f2bf(c.w) << 16);
  *(uint4*)(dst + idx) = o;
}

// ---------------------------------------------------------------------------
// L0 GEMM (K=128, single K-iteration): keep the proven 128x128-tile kernel.
template <int SWZ>
__global__ __launch_bounds__(256, 2) void gemm_tn(
    const unsigned short* __restrict__ A0, const unsigned short* __restrict__ B0,
    unsigned short* __restrict__ C0, int n0tiles, int ldc0,
    const unsigned short* __restrict__ A1, const unsigned short* __restrict__ B1,
    unsigned short* __restrict__ C1, int ldc1, int K) {
  __shared__ alignas(16) unsigned short Asl[128 * 128];
  __shared__ alignas(16) unsigned short Bsl[128 * 128];

  int mt, yt;
  if (SWZ) {
    int id = blockIdx.x;
    int xcd = id & 7, s = id >> 3;
    mt = ((xcd & 1) << 3) + (s & 7);
    yt = ((xcd >> 1) << 3) + (s >> 3);
  } else {
    mt = blockIdx.x;
    yt = blockIdx.y;
  }

  const unsigned short* A;
  const unsigned short* B;
  unsigned short* C;
  int ldc;
  if (yt < n0tiles) { A = A0; B = B0; C = C0; ldc = ldc0; }
  else { A = A1; B = B1; C = C1; ldc = ldc1; yt -= n0tiles; }

  const unsigned short* Ab = A + (size_t)mt * 128 * K;
  const unsigned short* Bb = B + (size_t)yt * 128 * K;

  const int tid = threadIdx.x;
  const int wave = tid >> 6, lane = tid & 63;
  const int mw = (wave >> 1) * 64, nw = (wave & 1) * 64;
  const int l16 = lane & 15, quad = lane >> 4;

  f32x4 acc[4][4] = {};

  for (int k0 = 0; k0 < K; k0 += 128) {
#pragma unroll
    for (int i = 0; i < 8; ++i) {
      int c = i * 256 + tid;
      int row = c >> 4;
      int l = (c & 15) ^ (row & 15);
      gld_lds16(Ab + (size_t)row * K + k0 + l * 8, &Asl[c * 8]);
      gld_lds16(Bb + (size_t)row * K + k0 + l * 8, &Bsl[c * 8]);
    }
    __syncthreads();

#pragma unroll
    for (int h = 0; h < 4; ++h) {
      bf16x8 af[4], bfr[4];
#pragma unroll
      for (int t = 0; t < 4; ++t) {
        int row = mw + t * 16 + l16;
        int p = (h * 4 + quad) ^ (row & 15);
        af[t] = *(const bf16x8*)&Asl[row * 128 + p * 8];
      }
#pragma unroll
      for (int t = 0; t < 4; ++t) {
        int row = nw + t * 16 + l16;
        int p = (h * 4 + quad) ^ (row & 15);
        bfr[t] = *(const bf16x8*)&Bsl[row * 128 + p * 8];
      }
#pragma unroll
      for (int tm = 0; tm < 4; ++tm)
#pragma unroll
        for (int tn = 0; tn < 4; ++tn)
          acc[tm][tn] = __builtin_amdgcn_mfma_f32_16x16x32_bf16(af[tm], bfr[tn], acc[tm][tn], 0, 0, 0);
    }
    __syncthreads();
  }

  const int mbase = mt * 128 + mw;
  const int nbase = yt * 128 + nw;
#pragma unroll
  for (int tm = 0; tm < 4; ++tm) {
#pragma unroll
    for (int tn = 0; tn < 4; ++tn) {
      int col = nbase + tn * 16 + l16;
      int row0 = mbase + tm * 16 + quad * 4;
#pragma unroll
      for (int r = 0; r < 4; ++r) {
        float v = fmaxf(acc[tm][tn][r], 0.0f);
        C[(size_t)(row0 + r) * ldc + col] = f2bf(v);
      }
    }
  }
}

// ---------------------------------------------------------------------------
// Hidden-layer GEMM, 8-phase-style pipelined (T3+T4+T5 per the catalog):
//   tile 256(M=samples) x 128(N=hidden), BK=64, 8 waves (4M x 2N, 64x64/wave),
//   tri-buffered LDS (3 x 48 KB = 144 KB -> 1 WG/CU, 256 WGs = exact fit),
//   counted s_waitcnt vmcnt(6) once per K-tile (never 0 mid-loop: tile t+2
//   always in flight), raw s_barrier (no compiler vmcnt(0) drain),
//   2 phases/K-tile each {stage 3 gld_lds || 8 ds_read_b128 || 16 MFMA} with
//   setprio around the MFMA cluster. XOR-swizzle (T2) as before.
// Hazards: slot (t+2)%3 last read in tile t-1, whose reads retire before that
//   wave's MFMAs; the tile-entry barrier orders them WG-wide -> staging safe.
//   vmcnt(6)+barrier at each tile boundary guarantees tile t+1's 6 loads
//   (oldest of 12 outstanding) landed across all waves before they're read.
__device__ __forceinline__ void stage_part8(const unsigned short* Ab,
                                            const unsigned short* Bb,
                                            unsigned short* As, unsigned short* Bs,
                                            int k0, int tid, int part, int K) {
#pragma unroll
  for (int i = part * 2; i < part * 2 + 2; ++i) {
    int c = i * 512 + tid;            // A chunk 0..2047 (256 rows x 8 chunks)
    int row = c >> 3, pc = c & 7;
    int l = pc ^ (row & 7);
    gld_lds16(Ab + (size_t)row * K + k0 + l * 8, As + c * 8);
  }
  {
    int c = part * 512 + tid;         // B chunk 0..1023 (128 rows x 8 chunks)
    int row = c >> 3, pc = c & 7;
    int l = pc ^ (row & 7);
    gld_lds16(Bb + (size_t)row * K + k0 + l * 8, Bs + c * 8);
  }
}

__device__ __forceinline__ bf16x8 ldfrag8(const unsigned short* S, int row, int p) {
  return *(const bf16x8*)&S[row * 64 + ((p ^ (row & 7)) * 8)];
}

__global__ __launch_bounds__(512, 2) void gemm_tn8(
    const unsigned short* __restrict__ A0, const unsigned short* __restrict__ B0,
    unsigned short* __restrict__ C0,
    const unsigned short* __restrict__ A1, const unsigned short* __restrict__ B1,
    unsigned short* __restrict__ C1, int K) {
  __shared__ alignas(16) unsigned short As[3][256 * 64];  // 3 x 32 KB
  __shared__ alignas(16) unsigned short Bs[3][128 * 64];  // 3 x 16 KB

  // Bijective XCD-chunked swizzle: XCD xcd owns N-tiles 4*xcd..4*xcd+3 for
  // all 8 M-tiles -> its B panel (4*128 rows x 2048 k x 2B = 2 MB) is
  // L2-resident across the whole K-loop; A (8 MB) streams via L3.
  const int id = blockIdx.x;          // 256 WGs
  const int xcd = id & 7, s = id >> 3;
  const int mt = s & 7;               // 8 M-tiles of 256 samples
  const int ntt = xcd * 4 + (s >> 3); // 32 N-tiles of 128 (0..15 chain0)

  const unsigned short* A;
  const unsigned short* B;
  unsigned short* C;
  int ntl;
  if (ntt < 16) { A = A0; B = B0; C = C0; ntl = ntt; }
  else          { A = A1; B = B1; C = C1; ntl = ntt - 16; }

  const unsigned short* Ab = A + (size_t)mt * 256 * K;
  const unsigned short* Bb = B + (size_t)ntl * 128 * K;

  const int tid = threadIdx.x;
  const int wave = tid >> 6, lane = tid & 63;
  const int mw = (wave >> 1) * 64;    // 4 M-wave rows: 0,64,128,192
  const int nw = (wave & 1) * 64;     // 2 N-wave cols: 0,64
  const int l16 = lane & 15, quad = lane >> 4;

  f32x4 acc[4][4] = {};
  const int NT = K >> 6;              // 32 K-tiles (K=2048)

  // Prologue: tiles 0 and 1 fully staged (12 loads/thread outstanding).
  stage_part8(Ab, Bb, As[0], Bs[0], 0, tid, 0, K);
  stage_part8(Ab, Bb, As[0], Bs[0], 0, tid, 1, K);
  stage_part8(Ab, Bb, As[1], Bs[1], 64, tid, 0, K);
  stage_part8(Ab, Bb, As[1], Bs[1], 64, tid, 1, K);
  asm volatile("s_waitcnt vmcnt(6)" ::: "memory");  // tile 0 landed (own wave)
  __builtin_amdgcn_s_barrier();                     // ... across all waves

  int cur = 0;
  for (int t = 0; t < NT; ++t) {
    asm volatile("" ::: "memory");    // no LDS reads hoist above entry barrier
    const int nxt2 = t + 2;
    int s2 = cur + 2; if (s2 >= 3) s2 -= 3;
    const int k2 = nxt2 << 6;

    // ---- phase 0 (k-sub h=0) ----
    if (nxt2 < NT) stage_part8(Ab, Bb, As[s2], Bs[s2], k2, tid, 0, K);
    bf16x8 a0[4], b0[4];
#pragma unroll
    for (int i = 0; i < 4; ++i) a0[i] = ldfrag8(&As[cur][0], mw + i * 16 + l16, quad);
#pragma unroll
    for (int i = 0; i < 4; ++i) b0[i] = ldfrag8(&Bs[cur][0], nw + i * 16 + l16, quad);
    __builtin_amdgcn_s_barrier();
    __builtin_amdgcn_s_setprio(1);
#pragma unroll
    for (int tm = 0; tm < 4; ++tm)
#pragma unroll
      for (int tn = 0; tn < 4; ++tn)
        acc[tm][tn] = __builtin_amdgcn_mfma_f32_16x16x32_bf16(a0[tm], b0[tn], acc[tm][tn], 0, 0, 0);
    __builtin_amdgcn_s_setprio(0);

    // ---- phase 1 (k-sub h=1) ----
    if (nxt2 < NT) stage_part8(Ab, Bb, As[s2], Bs[s2], k2, tid, 1, K);
    bf16x8 a1[4], b1[4];
#pragma unroll
    for (int i = 0; i < 4; ++i) a1[i] = ldfrag8(&As[cur][0], mw + i * 16 + l16, 4 + quad);
#pragma unroll
    for (int i = 0; i < 4; ++i) b1[i] = ldfrag8(&Bs[cur][0], nw + i * 16 + l16, 4 + quad);
    __builtin_amdgcn_s_barrier();
    __builtin_amdgcn_s_setprio(1);
#pragma unroll
    for (int tm = 0; tm < 4; ++tm)
#pragma unroll
      for (int tn = 0; tn < 4; ++tn)
        acc[tm][tn] = __builtin_amdgcn_mfma_f32_16x16x32_bf16(a1[tm], b1[tn], acc[tm][tn], 0, 0, 0);
    __builtin_amdgcn_s_setprio(0);

    // ---- tile boundary: ensure tile t+1 landed; release slot cur for WAR ----
    if (t + 1 < NT) {
      if (nxt2 < NT) asm volatile("s_waitcnt vmcnt(6)" ::: "memory");
      else           asm volatile("s_waitcnt vmcnt(0)" ::: "memory");
      __builtin_amdgcn_s_barrier();
    }
    ++cur; if (cur >= 3) cur = 0;
  }

  const int mbase = mt * 256 + mw;
  const int nbase = ntl * 128 + nw;
#pragma unroll
  for (int tm = 0; tm < 4; ++tm) {
#pragma unroll
    for (int tn = 0; tn < 4; ++tn) {
      int col = nbase + tn * 16 + l16;
      int row0 = mbase + tm * 16 + quad * 4;
#pragma unroll
      for (int r = 0; r < 4; ++r) {
        float v = fmaxf(acc[tm][tn][r], 0.0f);
        C[(size_t)(row0 + r) * 2048 + col] = f2bf(v);
      }
    }
  }
}

// ---------------------------------------------------------------------------
__device__ __forceinline__ void mm3(const float* a, const float* b, float* c) {
#pragma unroll
  for (int r = 0; r < 3; ++r)
#pragma unroll
    for (int cc = 0; cc < 3; ++cc)
      c[r * 3 + cc] = a[r * 3 + 0] * b[0 + cc] + a[r * 3 + 1] * b[3 + cc] + a[r * 3 + 2] * b[6 + cc];
}

__device__ __forceinline__ void expm3(const float* a, float* E) {
  // scaling-and-squaring + order-12 Taylor (scaled ||A||_1 <= 0.25)
  float n1 = 0.f;
#pragma unroll
  for (int c = 0; c < 3; ++c) {
    float s = fabsf(a[c]) + fabsf(a[3 + c]) + fabsf(a[6 + c]);
    n1 = fmaxf(n1, s);
  }
  int s = 0;
  if (n1 > 0.25f) {
    s = (int)ceilf(log2f(n1 * 4.0f));
    if (s < 0) s = 0;
  }
  const float scl = exp2f((float)(-s));
  float As[9];
#pragma unroll
  for (int i = 0; i < 9; ++i) As[i] = a[i] * scl;
  float T[9] = {1, 0, 0, 0, 1, 0, 0, 0, 1};
#pragma unroll
  for (int i = 0; i < 9; ++i) E[i] = T[i];
#pragma unroll
  for (int t = 1; t <= 12; ++t) {
    float Tn[9];
    mm3(T, As, Tn);
    const float inv = 1.0f / (float)t;
#pragma unroll
    for (int i = 0; i < 9; ++i) { T[i] = Tn[i] * inv; E[i] += T[i]; }
  }
  for (int q = 0; q < s; ++q) {
    float Tn[9];
    mm3(E, E, Tn);
#pragma unroll
    for (int i = 0; i < 9; ++i) E[i] = Tn[i];
  }
}

// ---------------------------------------------------------------------------
// Final layer + expm + output assembly, single kernel, no partials.
__global__ __launch_bounds__(256, 2) void gemm_l3(
    const unsigned short* __restrict__ Ho, const unsigned short* __restrict__ W9,
    const unsigned short* __restrict__ Ht, const unsigned short* __restrict__ W3,
    float* __restrict__ out) {
  __shared__ alignas(16) char smem[16384 + 39168];  // A 16 KB; B(36.9KB)/C(39.2KB) union
  unsigned short* Asl = (unsigned short*)smem;
  unsigned short* Bsl = (unsigned short*)(smem + 16384);
  float* Cl = (float*)(smem + 16384);

  const int mt = blockIdx.x;  // 32 tiles of 64 samples
  const int yt = blockIdx.y;  // 0..7 omega, 8..10 transl
  const int tid = threadIdx.x;
  const int wave = tid >> 6, lane = tid & 63;
  const int l16 = lane & 15, quad = lane >> 4;
  const int mbase = mt * 64;

  float* omega  = out;
  float* transf = out + (size_t)1152 * 2048;
  float* rot    = out + (size_t)(1152 + 1536) * 2048;
  float* transl = out + (size_t)(1152 + 1536 + 1152) * 2048;

  if (yt < 8) {
    const unsigned short* Ab = Ho + (size_t)mbase * 2048;
    const unsigned short* Bb = W9 + (size_t)yt * 144 * 2048;
    const int mw = wave * 16;
    f32x4 acc[9] = {};

    for (int k0 = 0; k0 < 2048; k0 += 128) {
#pragma unroll
      for (int i = 0; i < 4; ++i) {  // A: 64 rows x 16 chunks
        int c = i * 256 + tid;
        int row = c >> 4;
        int l = (c & 15) ^ (row & 15);
        gld_lds16(Ab + (size_t)row * 2048 + k0 + l * 8, &Asl[c * 8]);
      }
#pragma unroll
      for (int i = 0; i < 9; ++i) {  // B: 144 rows x 16 chunks
        int c = i * 256 + tid;
        int row = c >> 4;
        int l = (c & 15) ^ (row & 15);
        gld_lds16(Bb + (size_t)row * 2048 + k0 + l * 8, &Bsl[c * 8]);
      }
      __syncthreads();
#pragma unroll
      for (int h = 0; h < 4; ++h) {
        bf16x8 af;
        {
          int row = mw + l16;
          int p = (h * 4 + quad) ^ (row & 15);
          af = *(const bf16x8*)&Asl[row * 128 + p * 8];
        }
#pragma unroll
        for (int t = 0; t < 9; ++t) {
          int row = t * 16 + l16;
          int p = (h * 4 + quad) ^ (row & 15);
          bf16x8 bf = *(const bf16x8*)&Bsl[row * 128 + p * 8];
          acc[t] = __builtin_amdgcn_mfma_f32_16x16x32_bf16(af, bf, acc[t], 0, 0, 0);
        }
      }
      __syncthreads();
    }

    // C-tile -> LDS: Cl[dim * 68 + sample]  (dim 0..143 local, sample 0..63)
#pragma unroll
    for (int t = 0; t < 9; ++t) {
      int d = t * 16 + l16;
      int s0 = mw + quad * 4;
      *(f32x4*)&Cl[d * 68 + s0] = acc[t];
    }
    __syncthreads();

    const int jbase = yt * 16;
    const int k = mbase + lane;
#pragma unroll 1
    for (int pp = 0; pp < 4; ++pp) {
      int pl = wave * 4 + pp;  // local part 0..15
      int j = jbase + pl;
      float a[9];
#pragma unroll
      for (int i = 0; i < 9; ++i) a[i] = Cl[(pl * 9 + i) * 68 + lane];
#pragma unroll
      for (int i = 0; i < 9; ++i) omega[(size_t)(9 * j + i) * 2048 + k] = a[i];
      float E[9];
      expm3(a, E);
#pragma unroll
      for (int i = 0; i < 9; ++i) {
        rot[(size_t)(9 * j + i) * 2048 + k] = E[i];
        transf[(size_t)(12 * j + i) * 2048 + k] = E[i];
      }
    }
  } else {
    const int nt = yt - 8;
    const unsigned short* Ab = Ht + (size_t)mbase * 2048;
    const unsigned short* Bb = W3 + (size_t)nt * 128 * 2048;
    const int mw = (wave >> 1) * 32, nw = (wave & 1) * 64;
    f32x4 acc[2][4] = {};

    for (int k0 = 0; k0 < 2048; k0 += 128) {
#pragma unroll
      for (int i = 0; i < 4; ++i) {
        int c = i * 256 + tid;
        int row = c >> 4;
        int l = (c & 15) ^ (row & 15);
        gld_lds16(Ab + (size_t)row * 2048 + k0 + l * 8, &Asl[c * 8]);
      }
#pragma unroll
      for (int i = 0; i < 8; ++i) {
        int c = i * 256 + tid;
        int row = c >> 4;
        int l = (c & 15) ^ (row & 15);
        gld_lds16(Bb + (size_t)row * 2048 + k0 + l * 8, &Bsl[c * 8]);
      }
      __syncthreads();
#pragma unroll
      for (int h = 0; h < 4; ++h) {
        bf16x8 af[2], bfr[4];
#pragma unroll
        for (int t = 0; t < 2; ++t) {
          int row = mw + t * 16 + l16;
          int p = (h * 4 + quad) ^ (row & 15);
          af[t] = *(const bf16x8*)&Asl[row * 128 + p * 8];
        }
#pragma unroll
        for (int t = 0; t < 4; ++t) {
          int row = nw + t * 16 + l16;
          int p = (h * 4 + quad) ^ (row & 15);
          bfr[t] = *(const bf16x8*)&Bsl[row * 128 + p * 8];
        }
#pragma unroll
        for (int tm = 0; tm < 2; ++tm)
#pragma unroll
          for (int tn = 0; tn < 4; ++tn)
            acc[tm][tn] = __builtin_amdgcn_mfma_f32_16x16x32_bf16(af[tm], bfr[tn], acc[tm][tn], 0, 0, 0);
      }
      __syncthreads();
    }

    const int nbase = nt * 128 + nw;
#pragma unroll
    for (int tm = 0; tm < 2; ++tm) {
#pragma unroll
      for (int tn = 0; tn < 4; ++tn) {
        int n = nbase + tn * 16 + l16;       // 0..383
        int row0 = mbase + mw + tm * 16 + quad * 4;
        int j = n / 3, c = n % 3;
        *(f32x4*)&transl[(size_t)n * 2048 + row0] = acc[tm][tn];
        *(f32x4*)&transf[(size_t)(12 * j + 9 + c) * 2048 + row0] = acc[tm][tn];
      }
    }
  }
}

// ---------------------------------------------------------------------------
extern "C" void kernel_launch(void* const* d_in, const int* in_sizes, int n_in,
                              void* d_out, int out_size, void* d_ws, size_t ws_size,
                              hipStream_t stream) {
  const float* x   = (const float*)d_in[0];
  const float* Wo0 = (const float*)d_in[1];
  const float* Wo1 = (const float*)d_in[2];
  const float* Wo2 = (const float*)d_in[3];
  const float* Wo3 = (const float*)d_in[4];
  const float* Wt0 = (const float*)d_in[5];
  const float* Wt1 = (const float*)d_in[6];
  const float* Wt2 = (const float*)d_in[7];
  const float* Wt3 = (const float*)d_in[8];

  unsigned short* wb   = (unsigned short*)d_ws;
  unsigned short* wo0b = wb + 0;
  unsigned short* wo1b = wb + 262144;
  unsigned short* wo2b = wb + 4456448;
  unsigned short* wo3b = wb + 8650752;
  unsigned short* wt0b = wb + 11010048;
  unsigned short* wt1b = wb + 11272192;
  unsigned short* wt2b = wb + 15466496;
  unsigned short* wt3b = wb + 19660800;
  unsigned short* Xt   = wb + 20447232;  // 2048 x 128
  unsigned short* HoA  = Xt + 262144;    // 2048 x 2048 bf16 each
  unsigned short* HoB  = HoA + 4194304;
  unsigned short* HtA  = HoB + 4194304;
  unsigned short* HtB  = HtA + 4194304;
  // total ws use ~108 MB

  prep_k<<<10240, 256, 0, stream>>>(x, Wo0, Wo1, Wo2, Wo3, Wt0, Wt1, Wt2, Wt3, wb, Xt);

  // L0: K=128 -> single K-iteration (old 2-barrier kernel; latency-bound)
  gemm_tn<1><<<512, 256, 0, stream>>>(Xt, wo0b, HoA, 16, 2048,
                                      Xt, wt0b, HtA, 2048, 128);
  // L1/L2: pipelined 256x128 8-wave kernel with counted vmcnt
  gemm_tn8<<<256, 512, 0, stream>>>(HoA, wo1b, HoB, HtA, wt1b, HtB, 2048);
  gemm_tn8<<<256, 512, 0, stream>>>(HoB, wo2b, HoA, HtB, wt2b, HtA, 2048);
  // L3 + expm + all outputs
  gemm_l3<<<dim3(32, 11), 256, 0, stream>>>(HoA, wo3b, HtA, wt3b, (float*)d_out);
}

// Round 3
// 238.459 us; speedup vs baseline: 1.1815x; 1.1815x over previous
//
#include <hip/hip_runtime.h>
#include <stdint.h>

// LATENT=128, HIDDEN=2048, N_PARTS=128, K=2048
// outputs: omega(1152,2048) transf(1536,2048) rot(1152,2048) transl(384,2048)

typedef short bf16x8 __attribute__((ext_vector_type(8)));
typedef float f32x4 __attribute__((ext_vector_type(4)));

__device__ __forceinline__ unsigned short f2bf(float f) {
  unsigned int x = __float_as_uint(f);
  unsigned int r = (x + 0x7fffu + ((x >> 16) & 1u)) >> 16;
  return (unsigned short)r;
}

__device__ __forceinline__ void gld_lds16(const void* g, void* l) {
  __builtin_amdgcn_global_load_lds(
      (__attribute__((address_space(1))) void*)(g),
      (__attribute__((address_space(3))) void*)(l),
      16, 0, 0);
}

// LDS byte-offset of a generic pointer into __shared__ (AS3 ptrs are 32-bit).
__device__ __forceinline__ unsigned lds_addr(const void* p) {
  return (unsigned)(uintptr_t)(__attribute__((address_space(3))) const void*)p;
}

// Opaque ds_read_b128: no compiler alias tracking vs LDS-DMA, so no
// auto-inserted vmcnt(0) drains (the round-1 perf killer). Consumers MUST be
// fenced with lgkmcnt(0)+sched_barrier(0) (rule #18).
__device__ __forceinline__ bf16x8 ds_read128(unsigned a) {
  bf16x8 r;
  asm volatile("ds_read_b128 %0, %1" : "=v"(r) : "v"(a));
  return r;
}

#define ASM_BAR asm volatile("s_barrier" ::: "memory")
#define LGKM0   asm volatile("s_waitcnt lgkmcnt(0)" ::: "memory")
#define VMCNT0  asm volatile("s_waitcnt vmcnt(0)" ::: "memory")
#define SCHED0  __builtin_amdgcn_sched_barrier(0)

// ---------------------------------------------------------------------------
// Prep: blocks 0..9983 cast all 8 weights fp32->bf16 (8 elems/thread, 16 B
// stores); blocks 9984..10239 transpose+cast x (128x2048) -> Xt (2048x128).
__global__ void prep_k(const float* __restrict__ x,
                       const float* __restrict__ wo0, const float* __restrict__ wo1,
                       const float* __restrict__ wo2, const float* __restrict__ wo3,
                       const float* __restrict__ wt0, const float* __restrict__ wt1,
                       const float* __restrict__ wt2, const float* __restrict__ wt3,
                       unsigned short* __restrict__ dst, unsigned short* __restrict__ xt) {
  __shared__ float tile[32][33];
  const int b = blockIdx.x;
  const int tid = threadIdx.x;
  if (b >= 9984) {
    const int r = b - 9984;
    const int bx = r & 63, by = r >> 6;
    const int tx = tid & 31, ty = tid >> 5;
#pragma unroll
    for (int i = 0; i < 32; i += 8)
      tile[ty + i][tx] = x[(size_t)(by * 32 + ty + i) * 2048 + bx * 32 + tx];
    __syncthreads();
#pragma unroll
    for (int i = 0; i < 32; i += 8)
      xt[(size_t)(bx * 32 + ty + i) * 128 + by * 32 + tx] = f2bf(tile[tx][ty + i]);
    return;
  }
  int idx = (b * 256 + tid) * 8;
  if (idx >= 20447232) return;
  const float* src;
  int off;
  if (idx < 8650752) {
    if (idx < 262144)       { src = wo0; off = idx; }
    else if (idx < 4456448) { src = wo1; off = idx - 262144; }
    else                    { src = wo2; off = idx - 4456448; }
  } else {
    if (idx < 11010048)      { src = wo3; off = idx - 8650752; }
    else if (idx < 11272192) { src = wt0; off = idx - 11010048; }
    else if (idx < 15466496) { src = wt1; off = idx - 11272192; }
    else if (idx < 19660800) { src = wt2; off = idx - 15466496; }
    else                     { src = wt3; off = idx - 19660800; }
  }
  float4 a = *(const float4*)(src + off);
  float4 c = *(const float4*)(src + off + 4);
  uint4 o;
  o.x = (unsigned)f2bf(a.x) | ((unsigned)f2bf(a.y) << 16);
  o.y = (unsigned)f2bf(a.z) | ((unsigned)f2bf(a.w) << 16);
  o.z = (unsigned)f2bf(c.x) | ((unsigned)f2bf(c.y) << 16);
  o.w = (unsigned)f2bf(c.z) | ((unsigned)f2bf(c.w) << 16);
  *(uint4*)(dst + idx) = o;
}

// ---------------------------------------------------------------------------
// Proven 128x128-tile TN GEMM (2-barrier structure) — used for L0 and, this
// round, as the L2 within-run A/B control.
template <int SWZ>
__global__ __launch_bounds__(256, 2) void gemm_tn(
    const unsigned short* __restrict__ A0, const unsigned short* __restrict__ B0,
    unsigned short* __restrict__ C0, int n0tiles, int ldc0,
    const unsigned short* __restrict__ A1, const unsigned short* __restrict__ B1,
    unsigned short* __restrict__ C1, int ldc1, int K) {
  __shared__ alignas(16) unsigned short Asl[128 * 128];
  __shared__ alignas(16) unsigned short Bsl[128 * 128];

  int mt, yt;
  if (SWZ) {
    int id = blockIdx.x;
    int xcd = id & 7, s = id >> 3;
    mt = ((xcd & 1) << 3) + (s & 7);
    yt = ((xcd >> 1) << 3) + (s >> 3);
  } else {
    mt = blockIdx.x;
    yt = blockIdx.y;
  }

  const unsigned short* A;
  const unsigned short* B;
  unsigned short* C;
  int ldc;
  if (yt < n0tiles) { A = A0; B = B0; C = C0; ldc = ldc0; }
  else { A = A1; B = B1; C = C1; ldc = ldc1; yt -= n0tiles; }

  const unsigned short* Ab = A + (size_t)mt * 128 * K;
  const unsigned short* Bb = B + (size_t)yt * 128 * K;

  const int tid = threadIdx.x;
  const int wave = tid >> 6, lane = tid & 63;
  const int mw = (wave >> 1) * 64, nw = (wave & 1) * 64;
  const int l16 = lane & 15, quad = lane >> 4;

  f32x4 acc[4][4] = {};

  for (int k0 = 0; k0 < K; k0 += 128) {
#pragma unroll
    for (int i = 0; i < 8; ++i) {
      int c = i * 256 + tid;
      int row = c >> 4;
      int l = (c & 15) ^ (row & 15);
      gld_lds16(Ab + (size_t)row * K + k0 + l * 8, &Asl[c * 8]);
      gld_lds16(Bb + (size_t)row * K + k0 + l * 8, &Bsl[c * 8]);
    }
    __syncthreads();

#pragma unroll
    for (int h = 0; h < 4; ++h) {
      bf16x8 af[4], bfr[4];
#pragma unroll
      for (int t = 0; t < 4; ++t) {
        int row = mw + t * 16 + l16;
        int p = (h * 4 + quad) ^ (row & 15);
        af[t] = *(const bf16x8*)&Asl[row * 128 + p * 8];
      }
#pragma unroll
      for (int t = 0; t < 4; ++t) {
        int row = nw + t * 16 + l16;
        int p = (h * 4 + quad) ^ (row & 15);
        bfr[t] = *(const bf16x8*)&Bsl[row * 128 + p * 8];
      }
#pragma unroll
      for (int tm = 0; tm < 4; ++tm)
#pragma unroll
        for (int tn = 0; tn < 4; ++tn)
          acc[tm][tn] = __builtin_amdgcn_mfma_f32_16x16x32_bf16(af[tm], bfr[tn], acc[tm][tn], 0, 0, 0);
    }
    __syncthreads();
  }

  const int mbase = mt * 128 + mw;
  const int nbase = yt * 128 + nw;
#pragma unroll
  for (int tm = 0; tm < 4; ++tm) {
#pragma unroll
    for (int tn = 0; tn < 4; ++tn) {
      int col = nbase + tn * 16 + l16;
      int row0 = mbase + tm * 16 + quad * 4;
#pragma unroll
      for (int r = 0; r < 4; ++r) {
        float v = fmaxf(acc[tm][tn][r], 0.0f);
        C[(size_t)(row0 + r) * ldc + col] = f2bf(v);
      }
    }
  }
}

// ---------------------------------------------------------------------------
// Pipelined 256x128-tile GEMM, v3: the PROVABLY-SAFE minimum-2-phase schedule
// (guide m230-V0 template). Double-buffered LDS (96 KB, 1 WG/CU, 8 waves),
// BK=64. Per K-tile: STAGE(next tile) issued FIRST, then 16 asm ds_read_b128
// of the current tile, lgkmcnt(0)+sched_barrier, one 32-MFMA setprio cluster,
// then ONE vmcnt(0) + ONE s_barrier. Asm-opaque everywhere so the compiler
// cannot insert per-phase vmcnt(0) drains (round-1 killer).
// Hazard proof (no counted-vmcnt assumptions — round-2's v2 raced on those):
//   WAR: each wave's ds_reads of slot cur retire at its own LGKM0, before it
//        reaches the boundary barrier; STAGE of slot cur happens next iter,
//        after that barrier. RAW: each wave's STAGE(nxt) retires at its own
//        VMCNT0 before the barrier; reads of nxt happen after it.
__global__ __launch_bounds__(512, 2) void gemm_tn8(
    const unsigned short* __restrict__ A0, const unsigned short* __restrict__ B0,
    unsigned short* __restrict__ C0,
    const unsigned short* __restrict__ A1, const unsigned short* __restrict__ B1,
    unsigned short* __restrict__ C1, int K) {
  __shared__ alignas(16) unsigned short SM[2 * 16384 + 2 * 8192];  // A slots | B slots (96 KB)

  const int id = blockIdx.x;          // 256 WGs
  const int xcd = id & 7, s = id >> 3;
  const int mt = s & 7;               // 8 M-tiles of 256 samples
  const int ntt = xcd * 4 + (s >> 3); // 32 N-tiles of 128 (XCD owns 4 -> B L2-resident)

  const unsigned short* A;
  const unsigned short* B;
  unsigned short* C;
  int ntl;
  if (ntt < 16) { A = A0; B = B0; C = C0; ntl = ntt; }
  else          { A = A1; B = B1; C = C1; ntl = ntt - 16; }

  const unsigned short* Ab = A + (size_t)mt * 256 * K;
  const unsigned short* Bb = B + (size_t)ntl * 128 * K;

  const int tid = threadIdx.x;
  const int wave = tid >> 6, lane = tid & 63;
  const int mw = (wave >> 1) * 64;    // 0,64,128,192
  const int nw = (wave & 1) * 64;     // 0,64
  const int l16 = lane & 15, quad = lane >> 4;

  // Staging precompute: per-thread global srcs (swizzled chunk) + LDS dests
  // (linear, lane-contiguous as gld_lds requires).
  const unsigned short* gA[4];
  unsigned short* dA[4];
#pragma unroll
  for (int i = 0; i < 4; ++i) {
    int c = i * 512 + tid, row = c >> 3, pc = c & 7, l = pc ^ (row & 7);
    gA[i] = Ab + (size_t)row * K + l * 8;
    dA[i] = SM + c * 8;
  }
  const unsigned short* gB[2];
  unsigned short* dB[2];
#pragma unroll
  for (int j = 0; j < 2; ++j) {
    int c = j * 512 + tid, row = c >> 3, pc = c & 7, l = pc ^ (row & 7);
    gB[j] = Bb + (size_t)row * K + l * 8;
    dB[j] = SM + 32768 + c * 8;
  }

  // Fragment read byte-offsets (within a slot), k-sub phase 0/1.
  unsigned aoff[2][4], boff[2][4];
#pragma unroll
  for (int ph = 0; ph < 2; ++ph)
#pragma unroll
    for (int i = 0; i < 4; ++i) {
      int ra = mw + i * 16 + l16;
      aoff[ph][i] = (unsigned)(ra * 128 + (((ph * 4 + quad) ^ (ra & 7)) * 16));
      int rb = nw + i * 16 + l16;
      boff[ph][i] = (unsigned)(rb * 128 + (((ph * 4 + quad) ^ (rb & 7)) * 16));
    }
  const unsigned Au = lds_addr(SM);           // A slot s at Au + s*32768 B
  const unsigned Bu = Au + 65536;             // B slot s at Bu + s*16384 B

  f32x4 acc[4][4] = {};
  const int NT = K >> 6;                      // 32 K-tiles

  auto STAGE = [&](int slot, int k2) {
    const int sa = slot * 16384, sb = slot * 8192;  // shorts
#pragma unroll
    for (int i = 0; i < 4; ++i) gld_lds16(gA[i] + k2, dA[i] + sa);
#pragma unroll
    for (int j = 0; j < 2; ++j) gld_lds16(gB[j] + k2, dB[j] + sb);
  };

  // Prologue: tile 0 staged and drained.
  STAGE(0, 0);
  VMCNT0;
  ASM_BAR;

  int cur = 0;
  for (int t = 0; t < NT; ++t) {
    const int nxt = cur ^ 1;
    int k1 = (t + 1) << 6;
    if (k1 > K - 64) k1 = K - 64;   // last iter: redundant stage into dead slot
    STAGE(nxt, k1);                 // issue 6 loads; waited at end of THIS iter

    const unsigned ab = Au + cur * 32768, bb = Bu + cur * 16384;
    bf16x8 a0[4], b0[4], a1[4], b1[4];
#pragma unroll
    for (int i = 0; i < 4; ++i) a0[i] = ds_read128(ab + aoff[0][i]);
#pragma unroll
    for (int i = 0; i < 4; ++i) b0[i] = ds_read128(bb + boff[0][i]);
#pragma unroll
    for (int i = 0; i < 4; ++i) a1[i] = ds_read128(ab + aoff[1][i]);
#pragma unroll
    for (int i = 0; i < 4; ++i) b1[i] = ds_read128(bb + boff[1][i]);
    LGKM0;
    SCHED0;
    __builtin_amdgcn_s_setprio(1);
#pragma unroll
    for (int tm = 0; tm < 4; ++tm)
#pragma unroll
      for (int tn = 0; tn < 4; ++tn)
        acc[tm][tn] = __builtin_amdgcn_mfma_f32_16x16x32_bf16(a0[tm], b0[tn], acc[tm][tn], 0, 0, 0);
#pragma unroll
    for (int tm = 0; tm < 4; ++tm)
#pragma unroll
      for (int tn = 0; tn < 4; ++tn)
        acc[tm][tn] = __builtin_amdgcn_mfma_f32_16x16x32_bf16(a1[tm], b1[tn], acc[tm][tn], 0, 0, 0);
    __builtin_amdgcn_s_setprio(0);
    SCHED0;

    // ---- tile boundary: next tile landed (own stage), slot cur released ----
    VMCNT0;
    ASM_BAR;
    cur = nxt;
  }

  const int mbase = mt * 256 + mw;
  const int nbase = ntl * 128 + nw;
#pragma unroll
  for (int tm = 0; tm < 4; ++tm) {
#pragma unroll
    for (int tn = 0; tn < 4; ++tn) {
      int col = nbase + tn * 16 + l16;
      int row0 = mbase + tm * 16 + quad * 4;
#pragma unroll
      for (int r = 0; r < 4; ++r) {
        float v = fmaxf(acc[tm][tn][r], 0.0f);
        C[(size_t)(row0 + r) * 2048 + col] = f2bf(v);
      }
    }
  }
}

// ---------------------------------------------------------------------------
__device__ __forceinline__ void mm3(const float* a, const float* b, float* c) {
#pragma unroll
  for (int r = 0; r < 3; ++r)
#pragma unroll
    for (int cc = 0; cc < 3; ++cc)
      c[r * 3 + cc] = a[r * 3 + 0] * b[0 + cc] + a[r * 3 + 1] * b[3 + cc] + a[r * 3 + 2] * b[6 + cc];
}

__device__ __forceinline__ void expm3(const float* a, float* E) {
  // scaling-and-squaring + order-12 Taylor (scaled ||A||_1 <= 0.25)
  float n1 = 0.f;
#pragma unroll
  for (int c = 0; c < 3; ++c) {
    float s = fabsf(a[c]) + fabsf(a[3 + c]) + fabsf(a[6 + c]);
    n1 = fmaxf(n1, s);
  }
  int s = 0;
  if (n1 > 0.25f) {
    s = (int)ceilf(log2f(n1 * 4.0f));
    if (s < 0) s = 0;
  }
  const float scl = exp2f((float)(-s));
  float As[9];
#pragma unroll
  for (int i = 0; i < 9; ++i) As[i] = a[i] * scl;
  float T[9] = {1, 0, 0, 0, 1, 0, 0, 0, 1};
#pragma unroll
  for (int i = 0; i < 9; ++i) E[i] = T[i];
#pragma unroll
  for (int t = 1; t <= 12; ++t) {
    float Tn[9];
    mm3(T, As, Tn);
    const float inv = 1.0f / (float)t;
#pragma unroll
    for (int i = 0; i < 9; ++i) { T[i] = Tn[i] * inv; E[i] += T[i]; }
  }
  for (int q = 0; q < s; ++q) {
    float Tn[9];
    mm3(E, E, Tn);
#pragma unroll
    for (int i = 0; i < 9; ++i) E[i] = Tn[i];
  }
}

// ---------------------------------------------------------------------------
// Final layer + expm + output assembly, single kernel, no partials.
__global__ __launch_bounds__(256, 2) void gemm_l3(
    const unsigned short* __restrict__ Ho, const unsigned short* __restrict__ W9,
    const unsigned short* __restrict__ Ht, const unsigned short* __restrict__ W3,
    float* __restrict__ out) {
  __shared__ alignas(16) char smem[16384 + 39168];  // A 16 KB; B(36.9KB)/C(39.2KB) union
  unsigned short* Asl = (unsigned short*)smem;
  unsigned short* Bsl = (unsigned short*)(smem + 16384);
  float* Cl = (float*)(smem + 16384);

  const int mt = blockIdx.x;  // 32 tiles of 64 samples
  const int yt = blockIdx.y;  // 0..7 omega, 8..10 transl
  const int tid = threadIdx.x;
  const int wave = tid >> 6, lane = tid & 63;
  const int l16 = lane & 15, quad = lane >> 4;
  const int mbase = mt * 64;

  float* omega  = out;
  float* transf = out + (size_t)1152 * 2048;
  float* rot    = out + (size_t)(1152 + 1536) * 2048;
  float* transl = out + (size_t)(1152 + 1536 + 1152) * 2048;

  if (yt < 8) {
    const unsigned short* Ab = Ho + (size_t)mbase * 2048;
    const unsigned short* Bb = W9 + (size_t)yt * 144 * 2048;
    const int mw = wave * 16;
    f32x4 acc[9] = {};

    for (int k0 = 0; k0 < 2048; k0 += 128) {
#pragma unroll
      for (int i = 0; i < 4; ++i) {  // A: 64 rows x 16 chunks
        int c = i * 256 + tid;
        int row = c >> 4;
        int l = (c & 15) ^ (row & 15);
        gld_lds16(Ab + (size_t)row * 2048 + k0 + l * 8, &Asl[c * 8]);
      }
#pragma unroll
      for (int i = 0; i < 9; ++i) {  // B: 144 rows x 16 chunks
        int c = i * 256 + tid;
        int row = c >> 4;
        int l = (c & 15) ^ (row & 15);
        gld_lds16(Bb + (size_t)row * 2048 + k0 + l * 8, &Bsl[c * 8]);
      }
      __syncthreads();
#pragma unroll
      for (int h = 0; h < 4; ++h) {
        bf16x8 af;
        {
          int row = mw + l16;
          int p = (h * 4 + quad) ^ (row & 15);
          af = *(const bf16x8*)&Asl[row * 128 + p * 8];
        }
#pragma unroll
        for (int t = 0; t < 9; ++t) {
          int row = t * 16 + l16;
          int p = (h * 4 + quad) ^ (row & 15);
          bf16x8 bf = *(const bf16x8*)&Bsl[row * 128 + p * 8];
          acc[t] = __builtin_amdgcn_mfma_f32_16x16x32_bf16(af, bf, acc[t], 0, 0, 0);
        }
      }
      __syncthreads();
    }

    // C-tile -> LDS: Cl[dim * 68 + sample]  (dim 0..143 local, sample 0..63)
#pragma unroll
    for (int t = 0; t < 9; ++t) {
      int d = t * 16 + l16;
      int s0 = mw + quad * 4;
      *(f32x4*)&Cl[d * 68 + s0] = acc[t];
    }
    __syncthreads();

    const int jbase = yt * 16;
    const int k = mbase + lane;
#pragma unroll 1
    for (int pp = 0; pp < 4; ++pp) {
      int pl = wave * 4 + pp;  // local part 0..15
      int j = jbase + pl;
      float a[9];
#pragma unroll
      for (int i = 0; i < 9; ++i) a[i] = Cl[(pl * 9 + i) * 68 + lane];
#pragma unroll
      for (int i = 0; i < 9; ++i) omega[(size_t)(9 * j + i) * 2048 + k] = a[i];
      float E[9];
      expm3(a, E);
#pragma unroll
      for (int i = 0; i < 9; ++i) {
        rot[(size_t)(9 * j + i) * 2048 + k] = E[i];
        transf[(size_t)(12 * j + i) * 2048 + k] = E[i];
      }
    }
  } else {
    const int nt = yt - 8;
    const unsigned short* Ab = Ht + (size_t)mbase * 2048;
    const unsigned short* Bb = W3 + (size_t)nt * 128 * 2048;
    const int mw = (wave >> 1) * 32, nw = (wave & 1) * 64;
    f32x4 acc[2][4] = {};

    for (int k0 = 0; k0 < 2048; k0 += 128) {
#pragma unroll
      for (int i = 0; i < 4; ++i) {
        int c = i * 256 + tid;
        int row = c >> 4;
        int l = (c & 15) ^ (row & 15);
        gld_lds16(Ab + (size_t)row * 2048 + k0 + l * 8, &Asl[c * 8]);
      }
#pragma unroll
      for (int i = 0; i < 8; ++i) {
        int c = i * 256 + tid;
        int row = c >> 4;
        int l = (c & 15) ^ (row & 15);
        gld_lds16(Bb + (size_t)row * 2048 + k0 + l * 8, &Bsl[c * 8]);
      }
      __syncthreads();
#pragma unroll
      for (int h = 0; h < 4; ++h) {
        bf16x8 af[2], bfr[4];
#pragma unroll
        for (int t = 0; t < 2; ++t) {
          int row = mw + t * 16 + l16;
          int p = (h * 4 + quad) ^ (row & 15);
          af[t] = *(const bf16x8*)&Asl[row * 128 + p * 8];
        }
#pragma unroll
        for (int t = 0; t < 4; ++t) {
          int row = nw + t * 16 + l16;
          int p = (h * 4 + quad) ^ (row & 15);
          bfr[t] = *(const bf16x8*)&Bsl[row * 128 + p * 8];
        }
#pragma unroll
        for (int tm = 0; tm < 2; ++tm)
#pragma unroll
          for (int tn = 0; tn < 4; ++tn)
            acc[tm][tn] = __builtin_amdgcn_mfma_f32_16x16x32_bf16(af[tm], bfr[tn], acc[tm][tn], 0, 0, 0);
      }
      __syncthreads();
    }

    const int nbase = nt * 128 + nw;
#pragma unroll
    for (int tm = 0; tm < 2; ++tm) {
#pragma unroll
      for (int tn = 0; tn < 4; ++tn) {
        int n = nbase + tn * 16 + l16;       // 0..383
        int row0 = mbase + mw + tm * 16 + quad * 4;
        int j = n / 3, c = n % 3;
        *(f32x4*)&transl[(size_t)n * 2048 + row0] = acc[tm][tn];
        *(f32x4*)&transf[(size_t)(12 * j + 9 + c) * 2048 + row0] = acc[tm][tn];
      }
    }
  }
}

// ---------------------------------------------------------------------------
extern "C" void kernel_launch(void* const* d_in, const int* in_sizes, int n_in,
                              void* d_out, int out_size, void* d_ws, size_t ws_size,
                              hipStream_t stream) {
  const float* x   = (const float*)d_in[0];
  const float* Wo0 = (const float*)d_in[1];
  const float* Wo1 = (const float*)d_in[2];
  const float* Wo2 = (const float*)d_in[3];
  const float* Wo3 = (const float*)d_in[4];
  const float* Wt0 = (const float*)d_in[5];
  const float* Wt1 = (const float*)d_in[6];
  const float* Wt2 = (const float*)d_in[7];
  const float* Wt3 = (const float*)d_in[8];

  unsigned short* wb   = (unsigned short*)d_ws;
  unsigned short* wo0b = wb + 0;
  unsigned short* wo1b = wb + 262144;
  unsigned short* wo2b = wb + 4456448;
  unsigned short* wo3b = wb + 8650752;
  unsigned short* wt0b = wb + 11010048;
  unsigned short* wt1b = wb + 11272192;
  unsigned short* wt2b = wb + 15466496;
  unsigned short* wt3b = wb + 19660800;
  unsigned short* Xt   = wb + 20447232;  // 2048 x 128
  unsigned short* HoA  = Xt + 262144;    // 2048 x 2048 bf16 each
  unsigned short* HoB  = HoA + 4194304;
  unsigned short* HtA  = HoB + 4194304;
  unsigned short* HtB  = HtA + 4194304;
  // total ws use ~108 MB

  prep_k<<<10240, 256, 0, stream>>>(x, Wo0, Wo1, Wo2, Wo3, Wt0, Wt1, Wt2, Wt3, wb, Xt);

  // L0: K=128 -> single K-iteration (proven 2-barrier kernel)
  gemm_tn<1><<<512, 256, 0, stream>>>(Xt, wo0b, HoA, 16, 2048,
                                      Xt, wt0b, HtA, 2048, 128);
  // L1: pipelined v3 (EXPERIMENT) — airtight 2-phase, one vmcnt(0)+barrier/tile
  gemm_tn8<<<256, 512, 0, stream>>>(HoA, wo1b, HoB, HtA, wt1b, HtB, 2048);
  // L2: proven 2-barrier kernel (CONTROL, same shape as L1)
  gemm_tn<1><<<512, 256, 0, stream>>>(HoB, wo2b, HoA, 16, 2048,
                                      HtB, wt2b, HtA, 2048, 2048);
  // L3 + expm + all outputs
  gemm_l3<<<dim3(32, 11), 256, 0, stream>>>(HoA, wo3b, HtA, wt3b, (float*)d_out);
}

// Round 4
// 235.201 us; speedup vs baseline: 1.1978x; 1.0139x over previous
//
#include <hip/hip_runtime.h>
#include <stdint.h>

// LATENT=128, HIDDEN=2048, N_PARTS=128, K=2048
// outputs: omega(1152,2048) transf(1536,2048) rot(1152,2048) transl(384,2048)

typedef short bf16x8 __attribute__((ext_vector_type(8)));
typedef float f32x4 __attribute__((ext_vector_type(4)));

__device__ __forceinline__ unsigned short f2bf(float f) {
  unsigned int x = __float_as_uint(f);
  unsigned int r = (x + 0x7fffu + ((x >> 16) & 1u)) >> 16;
  return (unsigned short)r;
}

__device__ __forceinline__ void gld_lds16(const void* g, void* l) {
  __builtin_amdgcn_global_load_lds(
      (__attribute__((address_space(1))) void*)(g),
      (__attribute__((address_space(3))) void*)(l),
      16, 0, 0);
}

// LDS byte-offset of a generic pointer into __shared__ (AS3 ptrs are 32-bit).
__device__ __forceinline__ unsigned lds_addr(const void* p) {
  return (unsigned)(uintptr_t)(__attribute__((address_space(3))) const void*)p;
}

// Opaque ds_read_b128: no compiler alias tracking vs LDS-DMA, so no
// auto-inserted vmcnt(0) drains. Consumers MUST be fenced with
// lgkmcnt(0)+sched_barrier(0) (rule #18).
__device__ __forceinline__ bf16x8 ds_read128(unsigned a) {
  bf16x8 r;
  asm volatile("ds_read_b128 %0, %1" : "=v"(r) : "v"(a));
  return r;
}

#define ASM_BAR asm volatile("s_barrier" ::: "memory")
#define LGKM0   asm volatile("s_waitcnt lgkmcnt(0)" ::: "memory")
#define VMCNT0  asm volatile("s_waitcnt vmcnt(0)" ::: "memory")
#define SCHED0  __builtin_amdgcn_sched_barrier(0)

// ---------------------------------------------------------------------------
// Prep: blocks 0..9983 cast all 8 weights fp32->bf16 (8 elems/thread, 16 B
// stores); blocks 9984..10239 transpose+cast x (128x2048) -> Xt (2048x128).
__global__ void prep_k(const float* __restrict__ x,
                       const float* __restrict__ wo0, const float* __restrict__ wo1,
                       const float* __restrict__ wo2, const float* __restrict__ wo3,
                       const float* __restrict__ wt0, const float* __restrict__ wt1,
                       const float* __restrict__ wt2, const float* __restrict__ wt3,
                       unsigned short* __restrict__ dst, unsigned short* __restrict__ xt) {
  __shared__ float tile[32][33];
  const int b = blockIdx.x;
  const int tid = threadIdx.x;
  if (b >= 9984) {
    const int r = b - 9984;
    const int bx = r & 63, by = r >> 6;
    const int tx = tid & 31, ty = tid >> 5;
#pragma unroll
    for (int i = 0; i < 32; i += 8)
      tile[ty + i][tx] = x[(size_t)(by * 32 + ty + i) * 2048 + bx * 32 + tx];
    __syncthreads();
#pragma unroll
    for (int i = 0; i < 32; i += 8)
      xt[(size_t)(bx * 32 + ty + i) * 128 + by * 32 + tx] = f2bf(tile[tx][ty + i]);
    return;
  }
  int idx = (b * 256 + tid) * 8;
  if (idx >= 20447232) return;
  const float* src;
  int off;
  if (idx < 8650752) {
    if (idx < 262144)       { src = wo0; off = idx; }
    else if (idx < 4456448) { src = wo1; off = idx - 262144; }
    else                    { src = wo2; off = idx - 4456448; }
  } else {
    if (idx < 11010048)      { src = wo3; off = idx - 8650752; }
    else if (idx < 11272192) { src = wt0; off = idx - 11010048; }
    else if (idx < 15466496) { src = wt1; off = idx - 11272192; }
    else if (idx < 19660800) { src = wt2; off = idx - 15466496; }
    else                     { src = wt3; off = idx - 19660800; }
  }
  float4 a = *(const float4*)(src + off);
  float4 c = *(const float4*)(src + off + 4);
  uint4 o;
  o.x = (unsigned)f2bf(a.x) | ((unsigned)f2bf(a.y) << 16);
  o.y = (unsigned)f2bf(a.z) | ((unsigned)f2bf(a.w) << 16);
  o.z = (unsigned)f2bf(c.x) | ((unsigned)f2bf(c.y) << 16);
  o.w = (unsigned)f2bf(c.z) | ((unsigned)f2bf(c.w) << 16);
  *(uint4*)(dst + idx) = o;
}

// ---------------------------------------------------------------------------
// Proven 128x128-tile TN GEMM (2-barrier structure) — used for L0.
template <int SWZ>
__global__ __launch_bounds__(256, 2) void gemm_tn(
    const unsigned short* __restrict__ A0, const unsigned short* __restrict__ B0,
    unsigned short* __restrict__ C0, int n0tiles, int ldc0,
    const unsigned short* __restrict__ A1, const unsigned short* __restrict__ B1,
    unsigned short* __restrict__ C1, int ldc1, int K) {
  __shared__ alignas(16) unsigned short Asl[128 * 128];
  __shared__ alignas(16) unsigned short Bsl[128 * 128];

  int mt, yt;
  if (SWZ) {
    int id = blockIdx.x;
    int xcd = id & 7, s = id >> 3;
    mt = ((xcd & 1) << 3) + (s & 7);
    yt = ((xcd >> 1) << 3) + (s >> 3);
  } else {
    mt = blockIdx.x;
    yt = blockIdx.y;
  }

  const unsigned short* A;
  const unsigned short* B;
  unsigned short* C;
  int ldc;
  if (yt < n0tiles) { A = A0; B = B0; C = C0; ldc = ldc0; }
  else { A = A1; B = B1; C = C1; ldc = ldc1; yt -= n0tiles; }

  const unsigned short* Ab = A + (size_t)mt * 128 * K;
  const unsigned short* Bb = B + (size_t)yt * 128 * K;

  const int tid = threadIdx.x;
  const int wave = tid >> 6, lane = tid & 63;
  const int mw = (wave >> 1) * 64, nw = (wave & 1) * 64;
  const int l16 = lane & 15, quad = lane >> 4;

  f32x4 acc[4][4] = {};

  for (int k0 = 0; k0 < K; k0 += 128) {
#pragma unroll
    for (int i = 0; i < 8; ++i) {
      int c = i * 256 + tid;
      int row = c >> 4;
      int l = (c & 15) ^ (row & 15);
      gld_lds16(Ab + (size_t)row * K + k0 + l * 8, &Asl[c * 8]);
      gld_lds16(Bb + (size_t)row * K + k0 + l * 8, &Bsl[c * 8]);
    }
    __syncthreads();

#pragma unroll
    for (int h = 0; h < 4; ++h) {
      bf16x8 af[4], bfr[4];
#pragma unroll
      for (int t = 0; t < 4; ++t) {
        int row = mw + t * 16 + l16;
        int p = (h * 4 + quad) ^ (row & 15);
        af[t] = *(const bf16x8*)&Asl[row * 128 + p * 8];
      }
#pragma unroll
      for (int t = 0; t < 4; ++t) {
        int row = nw + t * 16 + l16;
        int p = (h * 4 + quad) ^ (row & 15);
        bfr[t] = *(const bf16x8*)&Bsl[row * 128 + p * 8];
      }
#pragma unroll
      for (int tm = 0; tm < 4; ++tm)
#pragma unroll
        for (int tn = 0; tn < 4; ++tn)
          acc[tm][tn] = __builtin_amdgcn_mfma_f32_16x16x32_bf16(af[tm], bfr[tn], acc[tm][tn], 0, 0, 0);
    }
    __syncthreads();
  }

  const int mbase = mt * 128 + mw;
  const int nbase = yt * 128 + nw;
#pragma unroll
  for (int tm = 0; tm < 4; ++tm) {
#pragma unroll
    for (int tn = 0; tn < 4; ++tn) {
      int col = nbase + tn * 16 + l16;
      int row0 = mbase + tm * 16 + quad * 4;
#pragma unroll
      for (int r = 0; r < 4; ++r) {
        float v = fmaxf(acc[tm][tn][r], 0.0f);
        C[(size_t)(row0 + r) * ldc + col] = f2bf(v);
      }
    }
  }
}

// ---------------------------------------------------------------------------
// v4: 128x128 tile, BK=64, 4 waves, double-buffered 64 KB LDS -> 2 WGs/CU,
// 512 WGs. EXACT round-3-verified wait protocol (no counted vmcnt):
//   STAGE(next tile) -> 16 asm ds_read_b128(cur) -> lgkmcnt(0)+sched_barrier
//   -> 32-MFMA setprio cluster -> vmcnt(0) -> s_barrier.
// Combines v3's prefetch cover (loads waited one full tile after issue) with
// control's co-resident-WG overlap (the piece v3 lacked at 1 WG/CU).
// Hazards (identical proof to round 3): WAR — reads of slot cur drained at
// own LGKM0 before boundary barrier; STAGE(cur) happens next iter after it.
// RAW — own STAGE(nxt) drained at own VMCNT0 before barrier; reads after.
__global__ __launch_bounds__(256, 2) void gemm_db128(
    const unsigned short* __restrict__ A0, const unsigned short* __restrict__ B0,
    unsigned short* __restrict__ C0,
    const unsigned short* __restrict__ A1, const unsigned short* __restrict__ B1,
    unsigned short* __restrict__ C1, int K) {
  __shared__ alignas(16) unsigned short SM[2 * 16384];  // slot: A[0,8192) B[8192,16384) shorts

  const int id = blockIdx.x;          // 512 WGs
  const int xcd = id & 7, s = id >> 3;          // s in [0,64)
  const int mt = s & 15;                        // 16 M-tiles of 128 samples
  const int ntt = xcd * 4 + (s >> 4);           // 32 N-tiles of 128; XCD owns 4 -> B L2-resident

  const unsigned short* A;
  const unsigned short* B;
  unsigned short* C;
  int ntl;
  if (ntt < 16) { A = A0; B = B0; C = C0; ntl = ntt; }
  else          { A = A1; B = B1; C = C1; ntl = ntt - 16; }

  const unsigned short* Ab = A + (size_t)mt * 128 * K;
  const unsigned short* Bb = B + (size_t)ntl * 128 * K;

  const int tid = threadIdx.x;
  const int wave = tid >> 6, lane = tid & 63;
  const int mw = (wave >> 1) * 64, nw = (wave & 1) * 64;
  const int l16 = lane & 15, quad = lane >> 4;

  // Staging precompute: 4 A-loads + 4 B-loads per thread per tile.
  const unsigned short* gA[4];
  const unsigned short* gB[4];
  int dAo[4], dBo[4];
#pragma unroll
  for (int i = 0; i < 4; ++i) {
    int c = i * 256 + tid;            // 0..1023: 128 rows x 8 chunks
    int row = c >> 3, pc = c & 7, l = pc ^ (row & 7);
    gA[i] = Ab + (size_t)row * K + l * 8;
    dAo[i] = c * 8;
    gB[i] = Bb + (size_t)row * K + l * 8;
    dBo[i] = 8192 + c * 8;
  }

  // Fragment read byte-offsets within a slot, k-sub phase 0/1.
  unsigned aoff[2][4], boff[2][4];
#pragma unroll
  for (int ph = 0; ph < 2; ++ph)
#pragma unroll
    for (int i = 0; i < 4; ++i) {
      int ra = mw + i * 16 + l16;
      aoff[ph][i] = (unsigned)(ra * 128 + (((ph * 4 + quad) ^ (ra & 7)) * 16));
      int rb = nw + i * 16 + l16;
      boff[ph][i] = (unsigned)(16384 + rb * 128 + (((ph * 4 + quad) ^ (rb & 7)) * 16));
    }
  const unsigned Au = lds_addr(SM);   // slot s at Au + s*32768 bytes

  f32x4 acc[4][4] = {};
  const int NT = K >> 6;              // 32 K-tiles

  auto STAGE = [&](int slot, int k1) {
    const int so = slot * 16384;      // shorts
#pragma unroll
    for (int i = 0; i < 4; ++i) gld_lds16(gA[i] + k1, SM + so + dAo[i]);
#pragma unroll
    for (int i = 0; i < 4; ++i) gld_lds16(gB[i] + k1, SM + so + dBo[i]);
  };

  // Prologue: tile 0 staged and drained.
  STAGE(0, 0);
  VMCNT0;
  ASM_BAR;

  int cur = 0;
  for (int t = 0; t < NT; ++t) {
    int k1 = (t + 1) << 6;
    if (k1 > K - 64) k1 = K - 64;     // last iter: redundant stage into dead slot
    STAGE(cur ^ 1, k1);               // 8 loads; waited at end of THIS iter

    const unsigned base = Au + cur * 32768;
    bf16x8 a0[4], b0[4], a1[4], b1[4];
#pragma unroll
    for (int i = 0; i < 4; ++i) a0[i] = ds_read128(base + aoff[0][i]);
#pragma unroll
    for (int i = 0; i < 4; ++i) b0[i] = ds_read128(base + boff[0][i]);
#pragma unroll
    for (int i = 0; i < 4; ++i) a1[i] = ds_read128(base + aoff[1][i]);
#pragma unroll
    for (int i = 0; i < 4; ++i) b1[i] = ds_read128(base + boff[1][i]);
    LGKM0;
    SCHED0;
    __builtin_amdgcn_s_setprio(1);
#pragma unroll
    for (int tm = 0; tm < 4; ++tm)
#pragma unroll
      for (int tn = 0; tn < 4; ++tn)
        acc[tm][tn] = __builtin_amdgcn_mfma_f32_16x16x32_bf16(a0[tm], b0[tn], acc[tm][tn], 0, 0, 0);
#pragma unroll
    for (int tm = 0; tm < 4; ++tm)
#pragma unroll
      for (int tn = 0; tn < 4; ++tn)
        acc[tm][tn] = __builtin_amdgcn_mfma_f32_16x16x32_bf16(a1[tm], b1[tn], acc[tm][tn], 0, 0, 0);
    __builtin_amdgcn_s_setprio(0);
    SCHED0;

    // ---- tile boundary: next tile landed (own stage), slot cur released ----
    VMCNT0;
    ASM_BAR;
    cur ^= 1;
  }

  const int mbase = mt * 128 + mw;
  const int nbase = ntl * 128 + nw;
#pragma unroll
  for (int tm = 0; tm < 4; ++tm) {
#pragma unroll
    for (int tn = 0; tn < 4; ++tn) {
      int col = nbase + tn * 16 + l16;
      int row0 = mbase + tm * 16 + quad * 4;
#pragma unroll
      for (int r = 0; r < 4; ++r) {
        float v = fmaxf(acc[tm][tn][r], 0.0f);
        C[(size_t)(row0 + r) * 2048 + col] = f2bf(v);
      }
    }
  }
}

// ---------------------------------------------------------------------------
__device__ __forceinline__ void mm3(const float* a, const float* b, float* c) {
#pragma unroll
  for (int r = 0; r < 3; ++r)
#pragma unroll
    for (int cc = 0; cc < 3; ++cc)
      c[r * 3 + cc] = a[r * 3 + 0] * b[0 + cc] + a[r * 3 + 1] * b[3 + cc] + a[r * 3 + 2] * b[6 + cc];
}

__device__ __forceinline__ void expm3(const float* a, float* E) {
  // scaling-and-squaring + order-12 Taylor (scaled ||A||_1 <= 0.25)
  float n1 = 0.f;
#pragma unroll
  for (int c = 0; c < 3; ++c) {
    float s = fabsf(a[c]) + fabsf(a[3 + c]) + fabsf(a[6 + c]);
    n1 = fmaxf(n1, s);
  }
  int s = 0;
  if (n1 > 0.25f) {
    s = (int)ceilf(log2f(n1 * 4.0f));
    if (s < 0) s = 0;
  }
  const float scl = exp2f((float)(-s));
  float As[9];
#pragma unroll
  for (int i = 0; i < 9; ++i) As[i] = a[i] * scl;
  float T[9] = {1, 0, 0, 0, 1, 0, 0, 0, 1};
#pragma unroll
  for (int i = 0; i < 9; ++i) E[i] = T[i];
#pragma unroll
  for (int t = 1; t <= 12; ++t) {
    float Tn[9];
    mm3(T, As, Tn);
    const float inv = 1.0f / (float)t;
#pragma unroll
    for (int i = 0; i < 9; ++i) { T[i] = Tn[i] * inv; E[i] += T[i]; }
  }
  for (int q = 0; q < s; ++q) {
    float Tn[9];
    mm3(E, E, Tn);
#pragma unroll
    for (int i = 0; i < 9; ++i) E[i] = Tn[i];
  }
}

// ---------------------------------------------------------------------------
// Final layer + expm + output assembly, single kernel, no partials.
__global__ __launch_bounds__(256, 2) void gemm_l3(
    const unsigned short* __restrict__ Ho, const unsigned short* __restrict__ W9,
    const unsigned short* __restrict__ Ht, const unsigned short* __restrict__ W3,
    float* __restrict__ out) {
  __shared__ alignas(16) char smem[16384 + 39168];  // A 16 KB; B(36.9KB)/C(39.2KB) union
  unsigned short* Asl = (unsigned short*)smem;
  unsigned short* Bsl = (unsigned short*)(smem + 16384);
  float* Cl = (float*)(smem + 16384);

  const int mt = blockIdx.x;  // 32 tiles of 64 samples
  const int yt = blockIdx.y;  // 0..7 omega, 8..10 transl
  const int tid = threadIdx.x;
  const int wave = tid >> 6, lane = tid & 63;
  const int l16 = lane & 15, quad = lane >> 4;
  const int mbase = mt * 64;

  float* omega  = out;
  float* transf = out + (size_t)1152 * 2048;
  float* rot    = out + (size_t)(1152 + 1536) * 2048;
  float* transl = out + (size_t)(1152 + 1536 + 1152) * 2048;

  if (yt < 8) {
    const unsigned short* Ab = Ho + (size_t)mbase * 2048;
    const unsigned short* Bb = W9 + (size_t)yt * 144 * 2048;
    const int mw = wave * 16;
    f32x4 acc[9] = {};

    for (int k0 = 0; k0 < 2048; k0 += 128) {
#pragma unroll
      for (int i = 0; i < 4; ++i) {  // A: 64 rows x 16 chunks
        int c = i * 256 + tid;
        int row = c >> 4;
        int l = (c & 15) ^ (row & 15);
        gld_lds16(Ab + (size_t)row * 2048 + k0 + l * 8, &Asl[c * 8]);
      }
#pragma unroll
      for (int i = 0; i < 9; ++i) {  // B: 144 rows x 16 chunks
        int c = i * 256 + tid;
        int row = c >> 4;
        int l = (c & 15) ^ (row & 15);
        gld_lds16(Bb + (size_t)row * 2048 + k0 + l * 8, &Bsl[c * 8]);
      }
      __syncthreads();
#pragma unroll
      for (int h = 0; h < 4; ++h) {
        bf16x8 af;
        {
          int row = mw + l16;
          int p = (h * 4 + quad) ^ (row & 15);
          af = *(const bf16x8*)&Asl[row * 128 + p * 8];
        }
#pragma unroll
        for (int t = 0; t < 9; ++t) {
          int row = t * 16 + l16;
          int p = (h * 4 + quad) ^ (row & 15);
          bf16x8 bf = *(const bf16x8*)&Bsl[row * 128 + p * 8];
          acc[t] = __builtin_amdgcn_mfma_f32_16x16x32_bf16(af, bf, acc[t], 0, 0, 0);
        }
      }
      __syncthreads();
    }

    // C-tile -> LDS: Cl[dim * 68 + sample]  (dim 0..143 local, sample 0..63)
#pragma unroll
    for (int t = 0; t < 9; ++t) {
      int d = t * 16 + l16;
      int s0 = mw + quad * 4;
      *(f32x4*)&Cl[d * 68 + s0] = acc[t];
    }
    __syncthreads();

    const int jbase = yt * 16;
    const int k = mbase + lane;
#pragma unroll 1
    for (int pp = 0; pp < 4; ++pp) {
      int pl = wave * 4 + pp;  // local part 0..15
      int j = jbase + pl;
      float a[9];
#pragma unroll
      for (int i = 0; i < 9; ++i) a[i] = Cl[(pl * 9 + i) * 68 + lane];
#pragma unroll
      for (int i = 0; i < 9; ++i) omega[(size_t)(9 * j + i) * 2048 + k] = a[i];
      float E[9];
      expm3(a, E);
#pragma unroll
      for (int i = 0; i < 9; ++i) {
        rot[(size_t)(9 * j + i) * 2048 + k] = E[i];
        transf[(size_t)(12 * j + i) * 2048 + k] = E[i];
      }
    }
  } else {
    const int nt = yt - 8;
    const unsigned short* Ab = Ht + (size_t)mbase * 2048;
    const unsigned short* Bb = W3 + (size_t)nt * 128 * 2048;
    const int mw = (wave >> 1) * 32, nw = (wave & 1) * 64;
    f32x4 acc[2][4] = {};

    for (int k0 = 0; k0 < 2048; k0 += 128) {
#pragma unroll
      for (int i = 0; i < 4; ++i) {
        int c = i * 256 + tid;
        int row = c >> 4;
        int l = (c & 15) ^ (row & 15);
        gld_lds16(Ab + (size_t)row * 2048 + k0 + l * 8, &Asl[c * 8]);
      }
#pragma unroll
      for (int i = 0; i < 8; ++i) {
        int c = i * 256 + tid;
        int row = c >> 4;
        int l = (c & 15) ^ (row & 15);
        gld_lds16(Bb + (size_t)row * 2048 + k0 + l * 8, &Bsl[c * 8]);
      }
      __syncthreads();
#pragma unroll
      for (int h = 0; h < 4; ++h) {
        bf16x8 af[2], bfr[4];
#pragma unroll
        for (int t = 0; t < 2; ++t) {
          int row = mw + t * 16 + l16;
          int p = (h * 4 + quad) ^ (row & 15);
          af[t] = *(const bf16x8*)&Asl[row * 128 + p * 8];
        }
#pragma unroll
        for (int t = 0; t < 4; ++t) {
          int row = nw + t * 16 + l16;
          int p = (h * 4 + quad) ^ (row & 15);
          bfr[t] = *(const bf16x8*)&Bsl[row * 128 + p * 8];
        }
#pragma unroll
        for (int tm = 0; tm < 2; ++tm)
#pragma unroll
          for (int tn = 0; tn < 4; ++tn)
            acc[tm][tn] = __builtin_amdgcn_mfma_f32_16x16x32_bf16(af[tm], bfr[tn], acc[tm][tn], 0, 0, 0);
      }
      __syncthreads();
    }

    const int nbase = nt * 128 + nw;
#pragma unroll
    for (int tm = 0; tm < 2; ++tm) {
#pragma unroll
      for (int tn = 0; tn < 4; ++tn) {
        int n = nbase + tn * 16 + l16;       // 0..383
        int row0 = mbase + mw + tm * 16 + quad * 4;
        int j = n / 3, c = n % 3;
        *(f32x4*)&transl[(size_t)n * 2048 + row0] = acc[tm][tn];
        *(f32x4*)&transf[(size_t)(12 * j + 9 + c) * 2048 + row0] = acc[tm][tn];
      }
    }
  }
}

// ---------------------------------------------------------------------------
extern "C" void kernel_launch(void* const* d_in, const int* in_sizes, int n_in,
                              void* d_out, int out_size, void* d_ws, size_t ws_size,
                              hipStream_t stream) {
  const float* x   = (const float*)d_in[0];
  const float* Wo0 = (const float*)d_in[1];
  const float* Wo1 = (const float*)d_in[2];
  const float* Wo2 = (const float*)d_in[3];
  const float* Wo3 = (const float*)d_in[4];
  const float* Wt0 = (const float*)d_in[5];
  const float* Wt1 = (const float*)d_in[6];
  const float* Wt2 = (const float*)d_in[7];
  const float* Wt3 = (const float*)d_in[8];

  unsigned short* wb   = (unsigned short*)d_ws;
  unsigned short* wo0b = wb + 0;
  unsigned short* wo1b = wb + 262144;
  unsigned short* wo2b = wb + 4456448;
  unsigned short* wo3b = wb + 8650752;
  unsigned short* wt0b = wb + 11010048;
  unsigned short* wt1b = wb + 11272192;
  unsigned short* wt2b = wb + 15466496;
  unsigned short* wt3b = wb + 19660800;
  unsigned short* Xt   = wb + 20447232;  // 2048 x 128
  unsigned short* HoA  = Xt + 262144;    // 2048 x 2048 bf16 each
  unsigned short* HoB  = HoA + 4194304;
  unsigned short* HtA  = HoB + 4194304;
  unsigned short* HtB  = HtA + 4194304;
  // total ws use ~108 MB

  prep_k<<<10240, 256, 0, stream>>>(x, Wo0, Wo1, Wo2, Wo3, Wt0, Wt1, Wt2, Wt3, wb, Xt);

  // L0: K=128 -> single K-iteration (proven 2-barrier kernel)
  gemm_tn<1><<<512, 256, 0, stream>>>(Xt, wo0b, HoA, 16, 2048,
                                      Xt, wt0b, HtA, 2048, 128);
  // L1/L2: v4 — dbuf-pipelined 128x128, 2 WGs/CU (prefetch cover + co-residency)
  gemm_db128<<<512, 256, 0, stream>>>(HoA, wo1b, HoB, HtA, wt1b, HtB, 2048);
  gemm_db128<<<512, 256, 0, stream>>>(HoB, wo2b, HoA, HtB, wt2b, HtA, 2048);
  // L3 + expm + all outputs
  gemm_l3<<<dim3(32, 11), 256, 0, stream>>>(HoA, wo3b, HtA, wt3b, (float*)d_out);
}

// Round 5
// 234.560 us; speedup vs baseline: 1.2011x; 1.0027x over previous
//
#include <hip/hip_runtime.h>
#include <stdint.h>

// LATENT=128, HIDDEN=2048, N_PARTS=128, K=2048
// outputs: omega(1152,2048) transf(1536,2048) rot(1152,2048) transl(384,2048)

typedef short bf16x8 __attribute__((ext_vector_type(8)));
typedef float f32x4 __attribute__((ext_vector_type(4)));

__device__ __forceinline__ unsigned short f2bf(float f) {
  unsigned int x = __float_as_uint(f);
  unsigned int r = (x + 0x7fffu + ((x >> 16) & 1u)) >> 16;
  return (unsigned short)r;
}

__device__ __forceinline__ void gld_lds16(const void* g, void* l) {
  __builtin_amdgcn_global_load_lds(
      (__attribute__((address_space(1))) void*)(g),
      (__attribute__((address_space(3))) void*)(l),
      16, 0, 0);
}

// LDS byte-offset of a generic pointer into __shared__ (AS3 ptrs are 32-bit).
__device__ __forceinline__ unsigned lds_addr(const void* p) {
  return (unsigned)(uintptr_t)(__attribute__((address_space(3))) const void*)p;
}

// Opaque ds_read_b128: no compiler alias tracking vs LDS-DMA, so no
// auto-inserted vmcnt(0) drains. Consumers MUST be fenced with
// lgkmcnt(0)+sched_barrier(0) (rule #18).
__device__ __forceinline__ bf16x8 ds_read128(unsigned a) {
  bf16x8 r;
  asm volatile("ds_read_b128 %0, %1" : "=v"(r) : "v"(a));
  return r;
}

#define ASM_BAR asm volatile("s_barrier" ::: "memory")
#define LGKM0   asm volatile("s_waitcnt lgkmcnt(0)" ::: "memory")
#define VMCNT0  asm volatile("s_waitcnt vmcnt(0)" ::: "memory")
#define SCHED0  __builtin_amdgcn_sched_barrier(0)

// ---------------------------------------------------------------------------
// Prep: blocks 0..9983 cast all 8 weights fp32->bf16 (8 elems/thread, 16 B
// stores); blocks 9984..10239 transpose+cast x (128x2048) -> Xt (2048x128).
__global__ void prep_k(const float* __restrict__ x,
                       const float* __restrict__ wo0, const float* __restrict__ wo1,
                       const float* __restrict__ wo2, const float* __restrict__ wo3,
                       const float* __restrict__ wt0, const float* __restrict__ wt1,
                       const float* __restrict__ wt2, const float* __restrict__ wt3,
                       unsigned short* __restrict__ dst, unsigned short* __restrict__ xt) {
  __shared__ float tile[32][33];
  const int b = blockIdx.x;
  const int tid = threadIdx.x;
  if (b >= 9984) {
    const int r = b - 9984;
    const int bx = r & 63, by = r >> 6;
    const int tx = tid & 31, ty = tid >> 5;
#pragma unroll
    for (int i = 0; i < 32; i += 8)
      tile[ty + i][tx] = x[(size_t)(by * 32 + ty + i) * 2048 + bx * 32 + tx];
    __syncthreads();
#pragma unroll
    for (int i = 0; i < 32; i += 8)
      xt[(size_t)(bx * 32 + ty + i) * 128 + by * 32 + tx] = f2bf(tile[tx][ty + i]);
    return;
  }
  int idx = (b * 256 + tid) * 8;
  if (idx >= 20447232) return;
  const float* src;
  int off;
  if (idx < 8650752) {
    if (idx < 262144)       { src = wo0; off = idx; }
    else if (idx < 4456448) { src = wo1; off = idx - 262144; }
    else                    { src = wo2; off = idx - 4456448; }
  } else {
    if (idx < 11010048)      { src = wo3; off = idx - 8650752; }
    else if (idx < 11272192) { src = wt0; off = idx - 11010048; }
    else if (idx < 15466496) { src = wt1; off = idx - 11272192; }
    else if (idx < 19660800) { src = wt2; off = idx - 15466496; }
    else                     { src = wt3; off = idx - 19660800; }
  }
  float4 a = *(const float4*)(src + off);
  float4 c = *(const float4*)(src + off + 4);
  uint4 o;
  o.x = (unsigned)f2bf(a.x) | ((unsigned)f2bf(a.y) << 16);
  o.y = (unsigned)f2bf(a.z) | ((unsigned)f2bf(a.w) << 16);
  o.z = (unsigned)f2bf(c.x) | ((unsigned)f2bf(c.y) << 16);
  o.w = (unsigned)f2bf(c.z) | ((unsigned)f2bf(c.w) << 16);
  *(uint4*)(dst + idx) = o;
}

// ---------------------------------------------------------------------------
// Proven 128x128-tile TN GEMM (2-barrier structure) — used for L0.
template <int SWZ>
__global__ __launch_bounds__(256, 2) void gemm_tn(
    const unsigned short* __restrict__ A0, const unsigned short* __restrict__ B0,
    unsigned short* __restrict__ C0, int n0tiles, int ldc0,
    const unsigned short* __restrict__ A1, const unsigned short* __restrict__ B1,
    unsigned short* __restrict__ C1, int ldc1, int K) {
  __shared__ alignas(16) unsigned short Asl[128 * 128];
  __shared__ alignas(16) unsigned short Bsl[128 * 128];

  int mt, yt;
  if (SWZ) {
    int id = blockIdx.x;
    int xcd = id & 7, s = id >> 3;
    mt = ((xcd & 1) << 3) + (s & 7);
    yt = ((xcd >> 1) << 3) + (s >> 3);
  } else {
    mt = blockIdx.x;
    yt = blockIdx.y;
  }

  const unsigned short* A;
  const unsigned short* B;
  unsigned short* C;
  int ldc;
  if (yt < n0tiles) { A = A0; B = B0; C = C0; ldc = ldc0; }
  else { A = A1; B = B1; C = C1; ldc = ldc1; yt -= n0tiles; }

  const unsigned short* Ab = A + (size_t)mt * 128 * K;
  const unsigned short* Bb = B + (size_t)yt * 128 * K;

  const int tid = threadIdx.x;
  const int wave = tid >> 6, lane = tid & 63;
  const int mw = (wave >> 1) * 64, nw = (wave & 1) * 64;
  const int l16 = lane & 15, quad = lane >> 4;

  f32x4 acc[4][4] = {};

  for (int k0 = 0; k0 < K; k0 += 128) {
#pragma unroll
    for (int i = 0; i < 8; ++i) {
      int c = i * 256 + tid;
      int row = c >> 4;
      int l = (c & 15) ^ (row & 15);
      gld_lds16(Ab + (size_t)row * K + k0 + l * 8, &Asl[c * 8]);
      gld_lds16(Bb + (size_t)row * K + k0 + l * 8, &Bsl[c * 8]);
    }
    __syncthreads();

#pragma unroll
    for (int h = 0; h < 4; ++h) {
      bf16x8 af[4], bfr[4];
#pragma unroll
      for (int t = 0; t < 4; ++t) {
        int row = mw + t * 16 + l16;
        int p = (h * 4 + quad) ^ (row & 15);
        af[t] = *(const bf16x8*)&Asl[row * 128 + p * 8];
      }
#pragma unroll
      for (int t = 0; t < 4; ++t) {
        int row = nw + t * 16 + l16;
        int p = (h * 4 + quad) ^ (row & 15);
        bfr[t] = *(const bf16x8*)&Bsl[row * 128 + p * 8];
      }
#pragma unroll
      for (int tm = 0; tm < 4; ++tm)
#pragma unroll
        for (int tn = 0; tn < 4; ++tn)
          acc[tm][tn] = __builtin_amdgcn_mfma_f32_16x16x32_bf16(af[tm], bfr[tn], acc[tm][tn], 0, 0, 0);
    }
    __syncthreads();
  }

  const int mbase = mt * 128 + mw;
  const int nbase = yt * 128 + nw;
#pragma unroll
  for (int tm = 0; tm < 4; ++tm) {
#pragma unroll
    for (int tn = 0; tn < 4; ++tn) {
      int col = nbase + tn * 16 + l16;
      int row0 = mbase + tm * 16 + quad * 4;
#pragma unroll
      for (int r = 0; r < 4; ++r) {
        float v = fmaxf(acc[tm][tn][r], 0.0f);
        C[(size_t)(row0 + r) * ldc + col] = f2bf(v);
      }
    }
  }
}

// ---------------------------------------------------------------------------
// v4: 128x128 tile, BK=64, 4 waves, double-buffered 64 KB LDS -> 2 WGs/CU,
// 512 WGs. Round-3-verified wait protocol (no counted vmcnt):
//   STAGE(next tile) -> 16 asm ds_read_b128(cur) -> lgkmcnt(0)+sched_barrier
//   -> 32-MFMA setprio cluster -> vmcnt(0) -> s_barrier.
__global__ __launch_bounds__(256, 2) void gemm_db128(
    const unsigned short* __restrict__ A0, const unsigned short* __restrict__ B0,
    unsigned short* __restrict__ C0,
    const unsigned short* __restrict__ A1, const unsigned short* __restrict__ B1,
    unsigned short* __restrict__ C1, int K) {
  __shared__ alignas(16) unsigned short SM[2 * 16384];  // slot: A[0,8192) B[8192,16384) shorts

  const int id = blockIdx.x;          // 512 WGs
  const int xcd = id & 7, s = id >> 3;          // s in [0,64)
  const int mt = s & 15;                        // 16 M-tiles of 128 samples
  const int ntt = xcd * 4 + (s >> 4);           // 32 N-tiles of 128; XCD owns 4 -> B L2-resident

  const unsigned short* A;
  const unsigned short* B;
  unsigned short* C;
  int ntl;
  if (ntt < 16) { A = A0; B = B0; C = C0; ntl = ntt; }
  else          { A = A1; B = B1; C = C1; ntl = ntt - 16; }

  const unsigned short* Ab = A + (size_t)mt * 128 * K;
  const unsigned short* Bb = B + (size_t)ntl * 128 * K;

  const int tid = threadIdx.x;
  const int wave = tid >> 6, lane = tid & 63;
  const int mw = (wave >> 1) * 64, nw = (wave & 1) * 64;
  const int l16 = lane & 15, quad = lane >> 4;

  // Staging precompute: 4 A-loads + 4 B-loads per thread per tile.
  const unsigned short* gA[4];
  const unsigned short* gB[4];
  int dAo[4], dBo[4];
#pragma unroll
  for (int i = 0; i < 4; ++i) {
    int c = i * 256 + tid;            // 0..1023: 128 rows x 8 chunks
    int row = c >> 3, pc = c & 7, l = pc ^ (row & 7);
    gA[i] = Ab + (size_t)row * K + l * 8;
    dAo[i] = c * 8;
    gB[i] = Bb + (size_t)row * K + l * 8;
    dBo[i] = 8192 + c * 8;
  }

  // Fragment read byte-offsets within a slot, k-sub phase 0/1.
  unsigned aoff[2][4], boff[2][4];
#pragma unroll
  for (int ph = 0; ph < 2; ++ph)
#pragma unroll
    for (int i = 0; i < 4; ++i) {
      int ra = mw + i * 16 + l16;
      aoff[ph][i] = (unsigned)(ra * 128 + (((ph * 4 + quad) ^ (ra & 7)) * 16));
      int rb = nw + i * 16 + l16;
      boff[ph][i] = (unsigned)(16384 + rb * 128 + (((ph * 4 + quad) ^ (rb & 7)) * 16));
    }
  const unsigned Au = lds_addr(SM);   // slot s at Au + s*32768 bytes

  f32x4 acc[4][4] = {};
  const int NT = K >> 6;              // 32 K-tiles

  auto STAGE = [&](int slot, int k1) {
    const int so = slot * 16384;      // shorts
#pragma unroll
    for (int i = 0; i < 4; ++i) gld_lds16(gA[i] + k1, SM + so + dAo[i]);
#pragma unroll
    for (int i = 0; i < 4; ++i) gld_lds16(gB[i] + k1, SM + so + dBo[i]);
  };

  // Prologue: tile 0 staged and drained.
  STAGE(0, 0);
  VMCNT0;
  ASM_BAR;

  int cur = 0;
  for (int t = 0; t < NT; ++t) {
    int k1 = (t + 1) << 6;
    if (k1 > K - 64) k1 = K - 64;     // last iter: redundant stage into dead slot
    STAGE(cur ^ 1, k1);               // 8 loads; waited at end of THIS iter

    const unsigned base = Au + cur * 32768;
    bf16x8 a0[4], b0[4], a1[4], b1[4];
#pragma unroll
    for (int i = 0; i < 4; ++i) a0[i] = ds_read128(base + aoff[0][i]);
#pragma unroll
    for (int i = 0; i < 4; ++i) b0[i] = ds_read128(base + boff[0][i]);
#pragma unroll
    for (int i = 0; i < 4; ++i) a1[i] = ds_read128(base + aoff[1][i]);
#pragma unroll
    for (int i = 0; i < 4; ++i) b1[i] = ds_read128(base + boff[1][i]);
    LGKM0;
    SCHED0;
    __builtin_amdgcn_s_setprio(1);
#pragma unroll
    for (int tm = 0; tm < 4; ++tm)
#pragma unroll
      for (int tn = 0; tn < 4; ++tn)
        acc[tm][tn] = __builtin_amdgcn_mfma_f32_16x16x32_bf16(a0[tm], b0[tn], acc[tm][tn], 0, 0, 0);
#pragma unroll
    for (int tm = 0; tm < 4; ++tm)
#pragma unroll
      for (int tn = 0; tn < 4; ++tn)
        acc[tm][tn] = __builtin_amdgcn_mfma_f32_16x16x32_bf16(a1[tm], b1[tn], acc[tm][tn], 0, 0, 0);
    __builtin_amdgcn_s_setprio(0);
    SCHED0;

    // ---- tile boundary: next tile landed (own stage), slot cur released ----
    VMCNT0;
    ASM_BAR;
    cur ^= 1;
  }

  const int mbase = mt * 128 + mw;
  const int nbase = ntl * 128 + nw;
#pragma unroll
  for (int tm = 0; tm < 4; ++tm) {
#pragma unroll
    for (int tn = 0; tn < 4; ++tn) {
      int col = nbase + tn * 16 + l16;
      int row0 = mbase + tm * 16 + quad * 4;
#pragma unroll
      for (int r = 0; r < 4; ++r) {
        float v = fmaxf(acc[tm][tn][r], 0.0f);
        C[(size_t)(row0 + r) * 2048 + col] = f2bf(v);
      }
    }
  }
}

// ---------------------------------------------------------------------------
__device__ __forceinline__ void mm3(const float* a, const float* b, float* c) {
#pragma unroll
  for (int r = 0; r < 3; ++r)
#pragma unroll
    for (int cc = 0; cc < 3; ++cc)
      c[r * 3 + cc] = a[r * 3 + 0] * b[0 + cc] + a[r * 3 + 1] * b[3 + cc] + a[r * 3 + 2] * b[6 + cc];
}

__device__ __forceinline__ void expm3(const float* a, float* E) {
  // scaling-and-squaring + order-12 Taylor (scaled ||A||_1 <= 0.25)
  float n1 = 0.f;
#pragma unroll
  for (int c = 0; c < 3; ++c) {
    float s = fabsf(a[c]) + fabsf(a[3 + c]) + fabsf(a[6 + c]);
    n1 = fmaxf(n1, s);
  }
  int s = 0;
  if (n1 > 0.25f) {
    s = (int)ceilf(log2f(n1 * 4.0f));
    if (s < 0) s = 0;
  }
  const float scl = exp2f((float)(-s));
  float As[9];
#pragma unroll
  for (int i = 0; i < 9; ++i) As[i] = a[i] * scl;
  float T[9] = {1, 0, 0, 0, 1, 0, 0, 0, 1};
#pragma unroll
  for (int i = 0; i < 9; ++i) E[i] = T[i];
#pragma unroll
  for (int t = 1; t <= 12; ++t) {
    float Tn[9];
    mm3(T, As, Tn);
    const float inv = 1.0f / (float)t;
#pragma unroll
    for (int i = 0; i < 9; ++i) { T[i] = Tn[i] * inv; E[i] += T[i]; }
  }
  for (int q = 0; q < s; ++q) {
    float Tn[9];
    mm3(E, E, Tn);
#pragma unroll
    for (int i = 0; i < 9; ++i) E[i] = Tn[i];
  }
}

// ---------------------------------------------------------------------------
// Final layer + expm + output assembly. Grid (32,11) and epilogue identical to
// the verified kernel; K-loops rewritten in the v4 protocol (BK=64 dbuf,
// asm-opaque: STAGE(next) -> asm ds_reads -> lgkmcnt(0)+sched_barrier ->
// setprio MFMA -> vmcnt(0) -> s_barrier). LDS: A 2x8KB + B 2x18KB = 52 KB,
// Cl (39.2 KB) aliases slots after the final drain+barrier -> 2 WGs/CU.
__global__ __launch_bounds__(256, 2) void gemm_l3(
    const unsigned short* __restrict__ Ho, const unsigned short* __restrict__ W9,
    const unsigned short* __restrict__ Ht, const unsigned short* __restrict__ W3,
    float* __restrict__ out) {
  __shared__ alignas(16) unsigned short SM[26624];  // 53248 B
  float* Cl = (float*)SM;                           // aliases slots (post-loop only)

  const int mt = blockIdx.x;  // 32 tiles of 64 samples
  const int yt = blockIdx.y;  // 0..7 omega, 8..10 transl
  const int tid = threadIdx.x;
  const int wave = tid >> 6, lane = tid & 63;
  const int l16 = lane & 15, quad = lane >> 4;
  const int mbase = mt * 64;

  float* omega  = out;
  float* transf = out + (size_t)1152 * 2048;
  float* rot    = out + (size_t)(1152 + 1536) * 2048;
  float* transl = out + (size_t)(1152 + 1536 + 1152) * 2048;

  const unsigned Au = lds_addr(SM);   // A slot s: Au + s*8192 bytes (64 rows x 128 B)
  const int NT = 32;                  // K=2048, BK=64

  if (yt < 8) {
    const unsigned short* Ab = Ho + (size_t)mbase * 2048;
    const unsigned short* Bb = W9 + (size_t)yt * 144 * 2048;
    const int mw = wave * 16;
    f32x4 acc[9] = {};

    // Staging: A 512 chunks (2/thread); B 1152 chunks (4/thread + tid<128).
    const unsigned short* gA[2];
    int dAo[2];
#pragma unroll
    for (int i = 0; i < 2; ++i) {
      int c = i * 256 + tid, row = c >> 3, pc = c & 7, l = pc ^ (row & 7);
      gA[i] = Ab + (size_t)row * 2048 + l * 8;
      dAo[i] = c * 8;
    }
    const unsigned short* gB[5];
    int dBo[5];
#pragma unroll
    for (int i = 0; i < 5; ++i) {
      int c = i * 256 + tid;          // i=4 only valid for tid<128 (c<1152)
      if (c > 1151) c = 1151;         // clamp addr calc; load predicated below
      int row = c >> 3, pc = c & 7, l = pc ^ (row & 7);
      gB[i] = Bb + (size_t)row * 2048 + l * 8;
      dBo[i] = 8192 + c * 8;          // B slot 0 base = 8192 shorts
    }
    const bool b5 = (tid < 128);

    auto STAGE = [&](int slot, int k1) {
      const int sa = slot * 4096, sb = slot * 9216;  // shorts
#pragma unroll
      for (int i = 0; i < 2; ++i) gld_lds16(gA[i] + k1, SM + sa + dAo[i]);
#pragma unroll
      for (int i = 0; i < 4; ++i) gld_lds16(gB[i] + k1, SM + sb + dBo[i]);
      if (b5) gld_lds16(gB[4] + k1, SM + sb + dBo[4]);
    };

    // Fragment byte-offsets within a slot (A row: mw+l16; B rows t*16+l16).
    unsigned aoff[2], boff[2][9];
#pragma unroll
    for (int ph = 0; ph < 2; ++ph) {
      int ra = mw + l16;
      aoff[ph] = (unsigned)(ra * 128 + (((ph * 4 + quad) ^ (ra & 7)) * 16));
#pragma unroll
      for (int t = 0; t < 9; ++t) {
        int rb = t * 16 + l16;
        boff[ph][t] = (unsigned)(16384 + rb * 128 + (((ph * 4 + quad) ^ (rb & 7)) * 16));
      }
    }

    STAGE(0, 0);
    VMCNT0;
    ASM_BAR;

    int cur = 0;
    for (int t = 0; t < NT; ++t) {
      int k1 = (t + 1) << 6;
      if (k1 > 2048 - 64) k1 = 2048 - 64;
      STAGE(cur ^ 1, k1);

      const unsigned ab = Au + cur * 8192;
      const unsigned bb = Au + cur * 18432;
      bf16x8 af0, af1, bf0[9], bf1[9];
      af0 = ds_read128(ab + aoff[0]);
#pragma unroll
      for (int i = 0; i < 9; ++i) bf0[i] = ds_read128(bb + boff[0][i]);
      af1 = ds_read128(ab + aoff[1]);
#pragma unroll
      for (int i = 0; i < 9; ++i) bf1[i] = ds_read128(bb + boff[1][i]);
      LGKM0;
      SCHED0;
      __builtin_amdgcn_s_setprio(1);
#pragma unroll
      for (int i = 0; i < 9; ++i)
        acc[i] = __builtin_amdgcn_mfma_f32_16x16x32_bf16(af0, bf0[i], acc[i], 0, 0, 0);
#pragma unroll
      for (int i = 0; i < 9; ++i)
        acc[i] = __builtin_amdgcn_mfma_f32_16x16x32_bf16(af1, bf1[i], acc[i], 0, 0, 0);
      __builtin_amdgcn_s_setprio(0);
      SCHED0;

      VMCNT0;
      ASM_BAR;
      cur ^= 1;
    }

    // C-tile -> LDS: Cl[dim * 68 + sample]  (dim 0..143 local, sample 0..63)
#pragma unroll
    for (int t = 0; t < 9; ++t) {
      int d = t * 16 + l16;
      int s0 = mw + quad * 4;
      *(f32x4*)&Cl[d * 68 + s0] = acc[t];
    }
    __syncthreads();

    const int jbase = yt * 16;
    const int k = mbase + lane;
#pragma unroll 1
    for (int pp = 0; pp < 4; ++pp) {
      int pl = wave * 4 + pp;  // local part 0..15
      int j = jbase + pl;
      float a[9];
#pragma unroll
      for (int i = 0; i < 9; ++i) a[i] = Cl[(pl * 9 + i) * 68 + lane];
#pragma unroll
      for (int i = 0; i < 9; ++i) omega[(size_t)(9 * j + i) * 2048 + k] = a[i];
      float E[9];
      expm3(a, E);
#pragma unroll
      for (int i = 0; i < 9; ++i) {
        rot[(size_t)(9 * j + i) * 2048 + k] = E[i];
        transf[(size_t)(12 * j + i) * 2048 + k] = E[i];
      }
    }
  } else {
    const int nt = yt - 8;
    const unsigned short* Ab = Ht + (size_t)mbase * 2048;
    const unsigned short* Bb = W3 + (size_t)nt * 128 * 2048;
    const int mw = (wave >> 1) * 32, nw = (wave & 1) * 64;
    f32x4 acc[2][4] = {};

    // Staging: A 512 chunks (2/thread); B 1024 chunks (4/thread).
    const unsigned short* gA[2];
    int dAo[2];
#pragma unroll
    for (int i = 0; i < 2; ++i) {
      int c = i * 256 + tid, row = c >> 3, pc = c & 7, l = pc ^ (row & 7);
      gA[i] = Ab + (size_t)row * 2048 + l * 8;
      dAo[i] = c * 8;
    }
    const unsigned short* gB[4];
    int dBo[4];
#pragma unroll
    for (int i = 0; i < 4; ++i) {
      int c = i * 256 + tid, row = c >> 3, pc = c & 7, l = pc ^ (row & 7);
      gB[i] = Bb + (size_t)row * 2048 + l * 8;
      dBo[i] = 8192 + c * 8;
    }

    auto STAGE = [&](int slot, int k1) {
      const int sa = slot * 4096, sb = slot * 8192;  // shorts
#pragma unroll
      for (int i = 0; i < 2; ++i) gld_lds16(gA[i] + k1, SM + sa + dAo[i]);
#pragma unroll
      for (int i = 0; i < 4; ++i) gld_lds16(gB[i] + k1, SM + sb + dBo[i]);
    };

    unsigned aoff[2][2], boff[2][4];
#pragma unroll
    for (int ph = 0; ph < 2; ++ph) {
#pragma unroll
      for (int t = 0; t < 2; ++t) {
        int ra = mw + t * 16 + l16;
        aoff[ph][t] = (unsigned)(ra * 128 + (((ph * 4 + quad) ^ (ra & 7)) * 16));
      }
#pragma unroll
      for (int t = 0; t < 4; ++t) {
        int rb = nw + t * 16 + l16;
        boff[ph][t] = (unsigned)(16384 + rb * 128 + (((ph * 4 + quad) ^ (rb & 7)) * 16));
      }
    }

    STAGE(0, 0);
    VMCNT0;
    ASM_BAR;

    int cur = 0;
    for (int t = 0; t < NT; ++t) {
      int k1 = (t + 1) << 6;
      if (k1 > 2048 - 64) k1 = 2048 - 64;
      STAGE(cur ^ 1, k1);

      const unsigned ab = Au + cur * 8192;
      const unsigned bb = Au + cur * 16384;
      bf16x8 a0[2], b0[4], a1[2], b1[4];
#pragma unroll
      for (int i = 0; i < 2; ++i) a0[i] = ds_read128(ab + aoff[0][i]);
#pragma unroll
      for (int i = 0; i < 4; ++i) b0[i] = ds_read128(bb + boff[0][i]);
#pragma unroll
      for (int i = 0; i < 2; ++i) a1[i] = ds_read128(ab + aoff[1][i]);
#pragma unroll
      for (int i = 0; i < 4; ++i) b1[i] = ds_read128(bb + boff[1][i]);
      LGKM0;
      SCHED0;
      __builtin_amdgcn_s_setprio(1);
#pragma unroll
      for (int tm = 0; tm < 2; ++tm)
#pragma unroll
        for (int tn = 0; tn < 4; ++tn)
          acc[tm][tn] = __builtin_amdgcn_mfma_f32_16x16x32_bf16(a0[tm], b0[tn], acc[tm][tn], 0, 0, 0);
#pragma unroll
      for (int tm = 0; tm < 2; ++tm)
#pragma unroll
        for (int tn = 0; tn < 4; ++tn)
          acc[tm][tn] = __builtin_amdgcn_mfma_f32_16x16x32_bf16(a1[tm], b1[tn], acc[tm][tn], 0, 0, 0);
      __builtin_amdgcn_s_setprio(0);
      SCHED0;

      VMCNT0;
      ASM_BAR;
      cur ^= 1;
    }

    const int nbase = nt * 128 + nw;
#pragma unroll
    for (int tm = 0; tm < 2; ++tm) {
#pragma unroll
      for (int tn = 0; tn < 4; ++tn) {
        int n = nbase + tn * 16 + l16;       // 0..383
        int row0 = mbase + mw + tm * 16 + quad * 4;
        int j = n / 3, c = n % 3;
        *(f32x4*)&transl[(size_t)n * 2048 + row0] = acc[tm][tn];
        *(f32x4*)&transf[(size_t)(12 * j + 9 + c) * 2048 + row0] = acc[tm][tn];
      }
    }
  }
}

// ---------------------------------------------------------------------------
extern "C" void kernel_launch(void* const* d_in, const int* in_sizes, int n_in,
                              void* d_out, int out_size, void* d_ws, size_t ws_size,
                              hipStream_t stream) {
  const float* x   = (const float*)d_in[0];
  const float* Wo0 = (const float*)d_in[1];
  const float* Wo1 = (const float*)d_in[2];
  const float* Wo2 = (const float*)d_in[3];
  const float* Wo3 = (const float*)d_in[4];
  const float* Wt0 = (const float*)d_in[5];
  const float* Wt1 = (const float*)d_in[6];
  const float* Wt2 = (const float*)d_in[7];
  const float* Wt3 = (const float*)d_in[8];

  unsigned short* wb   = (unsigned short*)d_ws;
  unsigned short* wo0b = wb + 0;
  unsigned short* wo1b = wb + 262144;
  unsigned short* wo2b = wb + 4456448;
  unsigned short* wo3b = wb + 8650752;
  unsigned short* wt0b = wb + 11010048;
  unsigned short* wt1b = wb + 11272192;
  unsigned short* wt2b = wb + 15466496;
  unsigned short* wt3b = wb + 19660800;
  unsigned short* Xt   = wb + 20447232;  // 2048 x 128
  unsigned short* HoA  = Xt + 262144;    // 2048 x 2048 bf16 each
  unsigned short* HoB  = HoA + 4194304;
  unsigned short* HtA  = HoB + 4194304;
  unsigned short* HtB  = HtA + 4194304;
  // total ws use ~108 MB

  prep_k<<<10240, 256, 0, stream>>>(x, Wo0, Wo1, Wo2, Wo3, Wt0, Wt1, Wt2, Wt3, wb, Xt);

  // L0: K=128 -> single K-iteration (proven 2-barrier kernel)
  gemm_tn<1><<<512, 256, 0, stream>>>(Xt, wo0b, HoA, 16, 2048,
                                      Xt, wt0b, HtA, 2048, 128);
  // L1/L2: v4 — dbuf-pipelined 128x128, 2 WGs/CU
  gemm_db128<<<512, 256, 0, stream>>>(HoA, wo1b, HoB, HtA, wt1b, HtB, 2048);
  gemm_db128<<<512, 256, 0, stream>>>(HoB, wo2b, HoA, HtB, wt2b, HtA, 2048);
  // L3 + expm + all outputs (v4-protocol K-loops)
  gemm_l3<<<dim3(32, 11), 256, 0, stream>>>(HoA, wo3b, HtA, wt3b, (float*)d_out);
}